// Round 1
// baseline (4508.475 us; speedup 1.0000x reference)
//
#include <hip/hip_runtime.h>
#include <math.h>

#define A_TOTAL 261120
#define B_BATCH 8
#define K_PER_LVL 1000
#define K_TOTAL 4000
#define NSORT 4096
#define POST_N 1000
#define NEGV -1e30f
#define BBOX_CLIP 4.135166556742356f

__device__ __forceinline__ unsigned sortable(float f) {
    unsigned u = __float_as_uint(f);
    return (u & 0x80000000u) ? ~u : (u | 0x80000000u);
}

__device__ __forceinline__ float unsortable(unsigned u) {
    return (u & 0x80000000u) ? __uint_as_float(u & 0x7FFFFFFFu) : __uint_as_float(~u);
}

// ---------------- Kernel 1: per-(batch,level) top-1000 via 3-pass radix select
__global__ __launch_bounds__(512) void topk_kernel(const float* __restrict__ obj,
                                                   int* __restrict__ sel) {
    const int offs[4] = {0, 196608, 245760, 258048};
    const int ns[4]   = {196608, 49152, 12288, 3072};
    int blk = blockIdx.x;           // 0..31
    int b = blk >> 2, lvl = blk & 3;
    int off = offs[lvl], n = ns[lvl];
    const float* src = obj + (size_t)b * A_TOTAL + off;

    __shared__ unsigned hist[2048];
    __shared__ unsigned s_T1, s_G1, s_T2, s_G2, s_T3, s_G3, s_cnt, s_eq;
    __shared__ int eqbuf[2048];
    int tid = threadIdx.x;

    // pass 1: top 11 bits
    for (int i = tid; i < 2048; i += 512) hist[i] = 0;
    __syncthreads();
    for (int i = tid; i < n; i += 512) atomicAdd(&hist[sortable(src[i]) >> 21], 1u);
    __syncthreads();
    if (tid == 0) {
        unsigned acc = 0; unsigned T = 0, G = 0;
        for (int bin = 2047; bin >= 0; --bin) {
            unsigned c = hist[bin];
            if (acc + c >= (unsigned)K_PER_LVL) { T = bin; G = acc; break; }
            acc += c;
        }
        s_T1 = T; s_G1 = G;
    }
    __syncthreads();
    unsigned T1 = s_T1, G1 = s_G1;

    // pass 2: bits 10..20 within bin T1
    for (int i = tid; i < 2048; i += 512) hist[i] = 0;
    __syncthreads();
    for (int i = tid; i < n; i += 512) {
        unsigned k = sortable(src[i]);
        if ((k >> 21) == T1) atomicAdd(&hist[(k >> 10) & 0x7FFu], 1u);
    }
    __syncthreads();
    if (tid == 0) {
        unsigned need = K_PER_LVL - G1;
        unsigned acc = 0; unsigned T = 0, G = 0;
        for (int bin = 2047; bin >= 0; --bin) {
            unsigned c = hist[bin];
            if (acc + c >= need) { T = bin; G = acc; break; }
            acc += c;
        }
        s_T2 = T; s_G2 = G;
    }
    __syncthreads();
    unsigned T2 = s_T2, G2 = s_G2;
    unsigned pref21 = (T1 << 11) | T2;   // bits 31..10

    // pass 3: bits 0..9 within prefix
    for (int i = tid; i < 1024; i += 512) hist[i] = 0;
    __syncthreads();
    for (int i = tid; i < n; i += 512) {
        unsigned k = sortable(src[i]);
        if ((k >> 10) == pref21) atomicAdd(&hist[k & 0x3FFu], 1u);
    }
    __syncthreads();
    if (tid == 0) {
        unsigned need = K_PER_LVL - G1 - G2;
        unsigned acc = 0; unsigned T = 0, G = 0;
        for (int bin = 1023; bin >= 0; --bin) {
            unsigned c = hist[bin];
            if (acc + c >= need) { T = bin; G = acc; break; }
            acc += c;
        }
        s_T3 = T; s_G3 = G; s_cnt = 0; s_eq = 0;
    }
    __syncthreads();
    unsigned Kstar = (pref21 << 10) | s_T3;
    unsigned Gtot = G1 + G2 + s_G3;     // count strictly greater than Kstar

    int* out = sel + (size_t)(b * 4 + lvl) * K_PER_LVL;
    for (int i = tid; i < n; i += 512) {
        unsigned k = sortable(src[i]);
        if (k > Kstar) {
            unsigned p = atomicAdd(&s_cnt, 1u);
            out[p] = off + i;
        } else if (k == Kstar) {
            unsigned p = atomicAdd(&s_eq, 1u);
            if (p < 2048) eqbuf[p] = i;
        }
    }
    __syncthreads();
    if (tid == 0) {
        int m = K_PER_LVL - (int)Gtot;          // how many equals to take
        int E = (int)min(s_eq, 2048u);
        int base = (int)Gtot;
        int last = -1;
        for (int r = 0; r < m; ++r) {           // m smallest indices among equals
            int best = 0x7FFFFFFF;
            for (int e = 0; e < E; ++e) {
                int v = eqbuf[e];
                if (v > last && v < best) best = v;
            }
            out[base + r] = off + best;
            last = best;
        }
    }
}

// ---------------- Kernel 2: per-image decode + sort + NMS + emit
__global__ __launch_bounds__(512) void nms_kernel(const float* __restrict__ obj,
                                                  const float* __restrict__ deltas,
                                                  const float* __restrict__ anchors,
                                                  const int* __restrict__ sel,
                                                  float* __restrict__ out_boxes,
                                                  float* __restrict__ out_scores) {
    int b = blockIdx.x;
    int tid = threadIdx.x;
    const int nth = 512;

    __shared__ unsigned long long key[NSORT];
    __shared__ float sx1[NSORT], sy1[NSORT], sx2[NSORT], sy2[NSORT];  // OFFSET coords
    __shared__ float sarea[NSORT];
    __shared__ signed char slv[NSORT];
    __shared__ unsigned char keep[NSORT];
    __shared__ int spos[NSORT];
    __shared__ int sV;

    // decode + build keys
    for (int s = tid; s < NSORT; s += nth) {
        if (s < K_TOTAL) {
            int g = sel[(size_t)b * K_TOTAL + s];
            float score = obj[(size_t)b * A_TOTAL + g];
            const float* dl = deltas + ((size_t)b * A_TOTAL + g) * 4;
            float ax1 = anchors[(size_t)g * 4 + 0], ay1 = anchors[(size_t)g * 4 + 1];
            float ax2 = anchors[(size_t)g * 4 + 2], ay2 = anchors[(size_t)g * 4 + 3];
            float wa = ax2 - ax1, ha = ay2 - ay1;
            float cxa = ax1 + 0.5f * wa, cya = ay1 + 0.5f * ha;
            float dx = dl[0], dy = dl[1];
            float dw = fminf(dl[2], BBOX_CLIP), dh = fminf(dl[3], BBOX_CLIP);
            float cx = dx * wa + cxa, cy = dy * ha + cya;
            float w = expf(dw) * wa, h = expf(dh) * ha;
            float x1 = cx - 0.5f * w, y1 = cy - 0.5f * h;
            float x2 = cx + 0.5f * w, y2 = cy + 0.5f * h;
            x1 = fminf(fmaxf(x1, 0.f), 1024.f);
            y1 = fminf(fmaxf(y1, 0.f), 1024.f);
            x2 = fminf(fmaxf(x2, 0.f), 1024.f);
            y2 = fminf(fmaxf(y2, 0.f), 1024.f);
            bool valid = (x2 - x1 >= 0.001f) && (y2 - y1 >= 0.001f) && (score >= 0.f);
            float sm = valid ? score : NEGV;
            int lv = (g >= 258048) ? 3 : (g >= 245760) ? 2 : (g >= 196608) ? 1 : 0;
            float lo = (float)lv * 1025.0f;
            float xo1 = x1 + lo, yo1 = y1 + lo, xo2 = x2 + lo, yo2 = y2 + lo;
            sx1[s] = xo1; sy1[s] = yo1; sx2[s] = xo2; sy2[s] = yo2;
            sarea[s] = (xo2 - xo1) * (yo2 - yo1);
            slv[s] = (signed char)lv;
            key[s] = ((unsigned long long)sortable(sm) << 32)
                   | ((unsigned long long)(0x3FFFFu - (unsigned)g) << 12)
                   | (unsigned)s;
        } else {
            sx1[s] = 0.f; sy1[s] = 0.f; sx2[s] = 0.f; sy2[s] = 0.f;
            sarea[s] = 0.f; slv[s] = -1;
            key[s] = ((unsigned long long)sortable(NEGV) << 32) | (unsigned)s;
        }
        keep[s] = 0;
    }
    __syncthreads();

    // bitonic sort descending (4096 keys)
    for (int k = 2; k <= NSORT; k <<= 1) {
        for (int j = k >> 1; j > 0; j >>= 1) {
            for (int i = tid; i < NSORT; i += nth) {
                int p = i ^ j;
                if (p > i) {
                    unsigned long long a = key[i], c = key[p];
                    bool up = (i & k) == 0;     // descending region
                    if (up ? (a < c) : (a > c)) { key[i] = c; key[p] = a; }
                }
            }
            __syncthreads();
        }
    }

    // count valid (score >= 0 => sortable >= 0x80000000)
    if (tid == 0) {
        int V = 0;
        while (V < K_TOTAL && (unsigned)(key[V] >> 32) >= 0x80000000u) ++V;
        sV = V;
    }
    __syncthreads();
    int V = sV;
    for (int i = tid; i < V; i += nth) keep[i] = 1;
    __syncthreads();

    // greedy NMS (sequential over i, parallel over j)
    for (int i = 0; i < V; ++i) {
        __syncthreads();
        if (!keep[i]) continue;
        int si = (int)(key[i] & 0xFFFu);
        float x1i = sx1[si], y1i = sy1[si], x2i = sx2[si], y2i = sy2[si];
        float ai = sarea[si];
        signed char li = slv[si];
        for (int jj = i + 1 + tid; jj < V; jj += nth) {
            if (!keep[jj]) continue;
            int sj = (int)(key[jj] & 0xFFFu);
            if (slv[sj] != li) continue;
            float lx = fmaxf(x1i, sx1[sj]);
            float ly = fmaxf(y1i, sy1[sj]);
            float rx = fminf(x2i, sx2[sj]);
            float ry = fminf(y2i, sy2[sj]);
            float wx = fmaxf(rx - lx, 0.f), wy = fmaxf(ry - ly, 0.f);
            float inter = wx * wy;
            float iou = inter / (ai + sarea[sj] - inter + 1e-9f);
            if (iou > 0.7f) keep[jj] = 0;
        }
    }
    __syncthreads();

    // compact kept positions
    if (tid == 0) {
        int p = 0;
        for (int i = 0; i < V; ++i) { spos[i] = keep[i] ? p : -1; if (keep[i]) ++p; }
        sV = p;
    }
    __syncthreads();

    float* ob = out_boxes + (size_t)b * POST_N * 4;
    float* os = out_scores + (size_t)b * POST_N;
    for (int q = tid; q < POST_N; q += nth) {
        ob[q * 4 + 0] = 0.f; ob[q * 4 + 1] = 0.f;
        ob[q * 4 + 2] = 0.f; ob[q * 4 + 3] = 0.f;
        os[q] = 0.f;
    }
    __syncthreads();
    for (int i = tid; i < V; i += nth) {
        int p = spos[i];
        if (p >= 0 && p < POST_N) {
            int s = (int)(key[i] & 0xFFFu);
            float lo = (float)slv[s] * 1025.0f;
            ob[p * 4 + 0] = sx1[s] - lo;
            ob[p * 4 + 1] = sy1[s] - lo;
            ob[p * 4 + 2] = sx2[s] - lo;
            ob[p * 4 + 3] = sy2[s] - lo;
            os[p] = unsortable((unsigned)(key[i] >> 32));
        }
    }
}

extern "C" void kernel_launch(void* const* d_in, const int* in_sizes, int n_in,
                              void* d_out, int out_size, void* d_ws, size_t ws_size,
                              hipStream_t stream) {
    const float* obj     = (const float*)d_in[0];  // [8, 261120]
    const float* deltas  = (const float*)d_in[1];  // [8, 261120, 4]
    const float* anchors = (const float*)d_in[2];  // [261120, 4]
    float* out_boxes  = (float*)d_out;                       // [8, 1000, 4]
    float* out_scores = (float*)d_out + B_BATCH * POST_N * 4; // [8, 1000]
    int* sel = (int*)d_ws;                                   // [8, 4000]

    topk_kernel<<<32, 512, 0, stream>>>(obj, sel);
    nms_kernel<<<B_BATCH, 512, 0, stream>>>(obj, deltas, anchors, sel,
                                            out_boxes, out_scores);
}

// Round 2
// 1408.696 us; speedup vs baseline: 3.2005x; 3.2005x over previous
//
#include <hip/hip_runtime.h>
#include <math.h>

#define A_TOTAL 261120
#define B_BATCH 8
#define K_PER_LVL 1000
#define K_TOTAL 4000
#define NSORT 4096
#define POST_N 1000
#define NEGV -1e30f
#define BBOX_CLIP 4.135166556742356f

__device__ __forceinline__ unsigned sortable(float f) {
    unsigned u = __float_as_uint(f);
    return (u & 0x80000000u) ? ~u : (u | 0x80000000u);
}

__device__ __forceinline__ float unsortable(unsigned u) {
    return (u & 0x80000000u) ? __uint_as_float(u & 0x7FFFFFFFu) : __uint_as_float(~u);
}

// Parallel "find threshold bin from top": hist[nb] in LDS, all 512 threads call.
// Result: s_res[0]=T (bin), s_res[1]=G (count strictly above bin T).
__device__ __forceinline__ void radix_select(unsigned* hist, int nb, unsigned need,
                                             unsigned* s_res, unsigned* swsum) {
    int tid = threadIdx.x;
    int per = nb >> 9;                 // bins per thread (4 or 2)
    unsigned vals[4];
    unsigned part = 0;
    for (int e = 0; e < per; ++e) {
        int bin = nb - 1 - (tid * per + e);   // reversed order: high bins first
        unsigned v = hist[bin];
        vals[e] = v; part += v;
    }
    int lane = tid & 63, wv = tid >> 6;
    unsigned x = part;
    #pragma unroll
    for (int d = 1; d < 64; d <<= 1) {
        unsigned y = __shfl_up(x, d);
        if (lane >= d) x += y;
    }
    if (lane == 63) swsum[wv] = x;
    __syncthreads();
    unsigned woff = 0;
    for (int w = 0; w < wv; ++w) woff += swsum[w];
    unsigned run = woff + x - part;    // exclusive prefix (count in bins above)
    for (int e = 0; e < per; ++e) {
        unsigned c = vals[e];
        if (run < need && run + c >= need) {
            s_res[0] = (unsigned)(nb - 1 - (tid * per + e));
            s_res[1] = run;
        }
        run += c;
    }
    __syncthreads();
}

// ---------------- Kernel 1: per-(batch,level) top-1000 via 3-pass radix select
__global__ __launch_bounds__(512) void topk_kernel(const float* __restrict__ obj,
                                                   int* __restrict__ sel) {
    const int offs[4] = {0, 196608, 245760, 258048};
    const int ns[4]   = {196608, 49152, 12288, 3072};
    int blk = blockIdx.x;           // 0..31
    int b = blk >> 2, lvl = blk & 3;
    int off = offs[lvl], n = ns[lvl];
    const float* src = obj + (size_t)b * A_TOTAL + off;
    const float4* src4 = (const float4*)src;
    int n4 = n >> 2;

    __shared__ unsigned whist[8 * 2048];
    __shared__ int eqbuf[2048];
    __shared__ unsigned s_res[2];
    __shared__ unsigned swsum[8];
    __shared__ unsigned s_cnt, s_eq;
    int tid = threadIdx.x;
    int wv = tid >> 6;

    for (int i = tid; i < 8 * 2048; i += 512) whist[i] = 0;
    if (tid == 0) { s_cnt = 0; s_eq = 0; }
    __syncthreads();

    // pass 1: top 11 bits, per-wave histograms
    unsigned* myh = whist + wv * 2048;
    for (int i = tid; i < n4; i += 512) {
        float4 v = src4[i];
        atomicAdd(&myh[sortable(v.x) >> 21], 1u);
        atomicAdd(&myh[sortable(v.y) >> 21], 1u);
        atomicAdd(&myh[sortable(v.z) >> 21], 1u);
        atomicAdd(&myh[sortable(v.w) >> 21], 1u);
    }
    __syncthreads();
    for (int bin = tid; bin < 2048; bin += 512) {
        unsigned s = 0;
        #pragma unroll
        for (int w = 0; w < 8; ++w) s += whist[w * 2048 + bin];
        whist[bin] = s;
    }
    __syncthreads();
    radix_select(whist, 2048, K_PER_LVL, s_res, swsum);
    unsigned T1 = s_res[0], G1 = s_res[1];

    // pass 2: bits 10..20 within bin T1
    for (int i = tid; i < 2048; i += 512) whist[i] = 0;
    __syncthreads();
    for (int i = tid; i < n4; i += 512) {
        float4 v = src4[i];
        unsigned k;
        k = sortable(v.x); if ((k >> 21) == T1) atomicAdd(&whist[(k >> 10) & 0x7FFu], 1u);
        k = sortable(v.y); if ((k >> 21) == T1) atomicAdd(&whist[(k >> 10) & 0x7FFu], 1u);
        k = sortable(v.z); if ((k >> 21) == T1) atomicAdd(&whist[(k >> 10) & 0x7FFu], 1u);
        k = sortable(v.w); if ((k >> 21) == T1) atomicAdd(&whist[(k >> 10) & 0x7FFu], 1u);
    }
    __syncthreads();
    radix_select(whist, 2048, K_PER_LVL - G1, s_res, swsum);
    unsigned T2 = s_res[0], G2 = s_res[1];
    unsigned pref21 = (T1 << 11) | T2;

    // pass 3: bits 0..9 within prefix
    for (int i = tid; i < 1024; i += 512) whist[i] = 0;
    __syncthreads();
    for (int i = tid; i < n4; i += 512) {
        float4 v = src4[i];
        unsigned k;
        k = sortable(v.x); if ((k >> 10) == pref21) atomicAdd(&whist[k & 0x3FFu], 1u);
        k = sortable(v.y); if ((k >> 10) == pref21) atomicAdd(&whist[k & 0x3FFu], 1u);
        k = sortable(v.z); if ((k >> 10) == pref21) atomicAdd(&whist[k & 0x3FFu], 1u);
        k = sortable(v.w); if ((k >> 10) == pref21) atomicAdd(&whist[k & 0x3FFu], 1u);
    }
    __syncthreads();
    radix_select(whist, 1024, K_PER_LVL - G1 - G2, s_res, swsum);
    unsigned T3 = s_res[0], G3 = s_res[1];
    unsigned Kstar = (pref21 << 10) | T3;
    unsigned Gtot = G1 + G2 + G3;

    int* out = sel + (size_t)(b * 4 + lvl) * K_PER_LVL;
    for (int i4 = tid; i4 < n4; i4 += 512) {
        float4 v = src4[i4];
        float arr[4] = {v.x, v.y, v.z, v.w};
        #pragma unroll
        for (int c = 0; c < 4; ++c) {
            unsigned k = sortable(arr[c]);
            int i = 4 * i4 + c;
            if (k > Kstar) {
                unsigned p = atomicAdd(&s_cnt, 1u);
                out[p] = off + i;
            } else if (k == Kstar) {
                unsigned p = atomicAdd(&s_eq, 1u);
                if (p < 2048) eqbuf[p] = i;
            }
        }
    }
    __syncthreads();
    if (tid == 0) {
        int m = K_PER_LVL - (int)Gtot;          // how many equals to take
        int E = (int)min(s_eq, 2048u);
        int base = (int)Gtot;
        int last = -1;
        for (int r = 0; r < m; ++r) {           // m smallest indices among equals
            int best = 0x7FFFFFFF;
            for (int e = 0; e < E; ++e) {
                int v = eqbuf[e];
                if (v > last && v < best) best = v;
            }
            out[base + r] = off + best;
            last = best;
        }
    }
}

// ---------------- Kernel 2: per-image decode + sort + blocked NMS + emit
__global__ __launch_bounds__(512) void nms_kernel(const float* __restrict__ obj,
                                                  const float* __restrict__ deltas,
                                                  const float* __restrict__ anchors,
                                                  const int* __restrict__ sel,
                                                  float* __restrict__ out_boxes,
                                                  float* __restrict__ out_scores) {
    int b = blockIdx.x;
    int tid = threadIdx.x;
    const int nth = 512;
    int lane = tid & 63, wvi = tid >> 6;

    __shared__ unsigned long long key[NSORT];                       // 32 KB
    __shared__ float bx1[NSORT], by1[NSORT], bx2[NSORT], by2[NSORT], bar[NSORT]; // 80 KB
    __shared__ unsigned char blv[NSORT];
    __shared__ unsigned char rm[NSORT];
    __shared__ unsigned long long srow[64];
    __shared__ unsigned long long s_alive;
    __shared__ int sV;
    __shared__ unsigned swsum[8];

    if (tid == 0) sV = K_TOTAL;

    // ---- decode into slot order (offset coords so levels never overlap)
    for (int s = tid; s < NSORT; s += nth) {
        if (s < K_TOTAL) {
            int g = sel[(size_t)b * K_TOTAL + s];
            float score = obj[(size_t)b * A_TOTAL + g];
            float4 dl = *(const float4*)(deltas + ((size_t)b * A_TOTAL + g) * 4);
            float4 an = *(const float4*)(anchors + (size_t)g * 4);
            float wa = an.z - an.x, ha = an.w - an.y;
            float cxa = an.x + 0.5f * wa, cya = an.y + 0.5f * ha;
            float dw = fminf(dl.z, BBOX_CLIP), dh = fminf(dl.w, BBOX_CLIP);
            float cx = dl.x * wa + cxa, cy = dl.y * ha + cya;
            float w = expf(dw) * wa, h = expf(dh) * ha;
            float x1 = cx - 0.5f * w, y1 = cy - 0.5f * h;
            float x2 = cx + 0.5f * w, y2 = cy + 0.5f * h;
            x1 = fminf(fmaxf(x1, 0.f), 1024.f);
            y1 = fminf(fmaxf(y1, 0.f), 1024.f);
            x2 = fminf(fmaxf(x2, 0.f), 1024.f);
            y2 = fminf(fmaxf(y2, 0.f), 1024.f);
            bool valid = (x2 - x1 >= 0.001f) && (y2 - y1 >= 0.001f) && (score >= 0.f);
            float sm = valid ? score : NEGV;
            int lv = (g >= 258048) ? 3 : (g >= 245760) ? 2 : (g >= 196608) ? 1 : 0;
            float lo = (float)lv * 1025.0f;
            float xo1 = x1 + lo, yo1 = y1 + lo, xo2 = x2 + lo, yo2 = y2 + lo;
            bx1[s] = xo1; by1[s] = yo1; bx2[s] = xo2; by2[s] = yo2;
            bar[s] = (xo2 - xo1) * (yo2 - yo1);
            blv[s] = (unsigned char)lv;
            key[s] = ((unsigned long long)sortable(sm) << 32)
                   | ((unsigned long long)(0x3FFFFu - (unsigned)g) << 12)
                   | (unsigned)s;
        } else {
            bx1[s] = 0.f; by1[s] = 0.f; bx2[s] = 0.f; by2[s] = 0.f;
            bar[s] = 0.f; blv[s] = 0;
            key[s] = ((unsigned long long)sortable(NEGV) << 32) | (unsigned)s;
        }
    }
    __syncthreads();

    // ---- bitonic sort descending (4096 keys)
    for (int k = 2; k <= NSORT; k <<= 1) {
        for (int j = k >> 1; j > 0; j >>= 1) {
            for (int i = tid; i < NSORT; i += nth) {
                int p = i ^ j;
                if (p > i) {
                    unsigned long long a = key[i], c = key[p];
                    bool up = (i & k) == 0;     // descending region
                    if (up ? (a < c) : (a > c)) { key[i] = c; key[p] = a; }
                }
            }
            __syncthreads();
        }
    }

    // ---- permute box data into sorted order; find V
    {
        float px1[8], py1[8], px2[8], py2[8], pa[8];
        unsigned char plv[8];
        #pragma unroll
        for (int e = 0; e < 8; ++e) {
            int i = tid * 8 + e;
            int slot = (int)(key[i] & 0xFFFull);
            px1[e] = bx1[slot]; py1[e] = by1[slot];
            px2[e] = bx2[slot]; py2[e] = by2[slot];
            pa[e] = bar[slot];  plv[e] = blv[slot];
            if (i < K_TOTAL && (unsigned)(key[i] >> 32) < 0x80000000u) atomicMin(&sV, i);
        }
        __syncthreads();
        #pragma unroll
        for (int e = 0; e < 8; ++e) {
            int i = tid * 8 + e;
            bx1[i] = px1[e]; by1[i] = py1[e];
            bx2[i] = px2[e]; by2[i] = py2[e];
            bar[i] = pa[e];  blv[i] = plv[e];
            rm[i] = 0;
        }
    }
    __syncthreads();
    int V = sV;

    // ---- blocked greedy NMS: 64-box chunks
    int nchunk = (V + 63) >> 6;
    int kept_total = 0;
    for (int c = 0; c < nchunk; ++c) {
        int base = c << 6;
        int j = base + lane;
        bool jin = j < V;
        float jx1 = bx1[j], jy1 = by1[j], jx2 = bx2[j], jy2 = by2[j], ja = bar[j];

        // A1: all waves build suppression rows (wave w owns rows w*8..w*8+7)
        #pragma unroll
        for (int kk = 0; kk < 8; ++kk) {
            int k = (wvi << 3) + kk;
            float kx1 = bx1[base + k], ky1 = by1[base + k];
            float kx2 = bx2[base + k], ky2 = by2[base + k], ka = bar[base + k];
            bool sup = false;
            if (jin && lane > k) {
                float lx = fmaxf(kx1, jx1), ly = fmaxf(ky1, jy1);
                float rx = fminf(kx2, jx2), ry = fminf(ky2, jy2);
                float wx = fmaxf(rx - lx, 0.f), wy = fmaxf(ry - ly, 0.f);
                float inter = wx * wy;
                float iou = inter / (ka + ja - inter + 1e-9f);
                sup = iou > 0.7f;
            }
            unsigned long long r = __ballot(sup);
            if (lane == 0) srow[k] = r;
        }
        __syncthreads();

        // A2: wave 0 resolves the chunk in registers (greedy, ascending k)
        if (wvi == 0) {
            unsigned long long row = srow[lane];
            bool a0 = jin && (rm[j] == 0);
            unsigned long long alive = __ballot(a0);
            unsigned long long m = alive;
            while (m) {
                int k = __ffsll(m) - 1;
                unsigned long long r = __shfl(row, k);
                alive &= ~r;            // row only has bits > k
                m &= alive;
                m &= ~(1ULL << k);
            }
            if (jin && a0 && !((alive >> lane) & 1)) rm[j] = 1;
            if (lane == 0) s_alive = alive;
        }
        __syncthreads();

        unsigned long long aliveC = s_alive;
        kept_total += __popcll(aliveC);
        if (kept_total >= POST_N) break;   // first 1000 kept already determined

        // B: all threads suppress later boxes vs this chunk's kept set
        for (int i = base + 64 + tid; i < V; i += nth) {
            if (rm[i]) continue;
            float ix1 = bx1[i], iy1 = by1[i], ix2 = bx2[i], iy2 = by2[i], ia = bar[i];
            unsigned long long mm = aliveC;
            bool dead = false;
            while (mm) {
                int k = __ffsll(mm) - 1; mm &= mm - 1;
                float kx1 = bx1[base + k], ky1 = by1[base + k];
                float kx2 = bx2[base + k], ky2 = by2[base + k], ka = bar[base + k];
                float lx = fmaxf(kx1, ix1), ly = fmaxf(ky1, iy1);
                float rx = fminf(kx2, ix2), ry = fminf(ky2, iy2);
                float wx = fmaxf(rx - lx, 0.f), wy = fmaxf(ry - ly, 0.f);
                float inter = wx * wy;
                float iou = inter / (ka + ia - inter + 1e-9f);
                if (iou > 0.7f) { dead = true; break; }
            }
            if (dead) rm[i] = 1;
        }
        __syncthreads();
    }
    __syncthreads();

    // ---- output: zero fill, then parallel prefix scan over kept flags
    float* ob = out_boxes + (size_t)b * POST_N * 4;
    float* os = out_scores + (size_t)b * POST_N;
    for (int q = tid; q < POST_N; q += nth) {
        ob[4 * q + 0] = 0.f; ob[4 * q + 1] = 0.f;
        ob[4 * q + 2] = 0.f; ob[4 * q + 3] = 0.f;
        os[q] = 0.f;
    }
    __syncthreads();

    int cnt = 0;
    unsigned char kf[8];
    #pragma unroll
    for (int e = 0; e < 8; ++e) {
        int i = tid * 8 + e;
        int f = (i < V && rm[i] == 0) ? 1 : 0;
        kf[e] = (unsigned char)f; cnt += f;
    }
    int x = cnt;
    #pragma unroll
    for (int d = 1; d < 64; d <<= 1) {
        int y = __shfl_up(x, d);
        if (lane >= d) x += y;
    }
    if (lane == 63) swsum[wvi] = (unsigned)x;
    __syncthreads();
    int woff = 0;
    for (int w = 0; w < wvi; ++w) woff += (int)swsum[w];
    int p = woff + x - cnt;      // exclusive prefix for this thread's 8 entries
    #pragma unroll
    for (int e = 0; e < 8; ++e) {
        if (kf[e]) {
            if (p < POST_N) {
                int i = tid * 8 + e;
                float lo = (float)blv[i] * 1025.0f;
                ob[4 * p + 0] = bx1[i] - lo;
                ob[4 * p + 1] = by1[i] - lo;
                ob[4 * p + 2] = bx2[i] - lo;
                ob[4 * p + 3] = by2[i] - lo;
                os[p] = unsortable((unsigned)(key[i] >> 32));
            }
            ++p;
        }
    }
}

extern "C" void kernel_launch(void* const* d_in, const int* in_sizes, int n_in,
                              void* d_out, int out_size, void* d_ws, size_t ws_size,
                              hipStream_t stream) {
    const float* obj     = (const float*)d_in[0];  // [8, 261120]
    const float* deltas  = (const float*)d_in[1];  // [8, 261120, 4]
    const float* anchors = (const float*)d_in[2];  // [261120, 4]
    float* out_boxes  = (float*)d_out;                        // [8, 1000, 4]
    float* out_scores = (float*)d_out + B_BATCH * POST_N * 4; // [8, 1000]
    int* sel = (int*)d_ws;                                    // [8, 4000]

    topk_kernel<<<32, 512, 0, stream>>>(obj, sel);
    nms_kernel<<<B_BATCH, 512, 0, stream>>>(obj, deltas, anchors, sel,
                                            out_boxes, out_scores);
}

// Round 3
// 458.866 us; speedup vs baseline: 9.8253x; 3.0700x over previous
//
#include <hip/hip_runtime.h>
#include <math.h>

#define A_TOTAL 261120
#define B_BATCH 8
#define K_PER_LVL 1000
#define K_TOTAL 4000
#define NSORT 4096
#define POST_N 1000
#define NEGV -1e30f
#define BBOX_CLIP 4.135166556742356f

typedef unsigned long long u64;

__device__ __forceinline__ unsigned sortable(float f) {
    unsigned u = __float_as_uint(f);
    return (u & 0x80000000u) ? ~u : (u | 0x80000000u);
}

__device__ __forceinline__ float unsortable(unsigned u) {
    return (u & 0x80000000u) ? __uint_as_float(u & 0x7FFFFFFFu) : __uint_as_float(~u);
}

// Parallel "find threshold bin from top" over hist[NB]; all 512 threads call.
// Result: s_res[0]=T (bin), s_res[1]=G (count strictly above bin T).
template<int NB>
__device__ __forceinline__ void radix_sel(unsigned* hist, unsigned need,
                                          unsigned* s_res, unsigned* swsum) {
    const int per = NB >> 9;
    int tid = threadIdx.x;
    unsigned vals[per];
    unsigned part = 0;
    #pragma unroll
    for (int e = 0; e < per; ++e) {
        unsigned v = hist[NB - 1 - (tid * per + e)];   // high bins first
        vals[e] = v; part += v;
    }
    int lane = tid & 63, wv = tid >> 6;
    unsigned x = part;
    #pragma unroll
    for (int d = 1; d < 64; d <<= 1) {
        unsigned y = __shfl_up(x, d);
        if (lane >= d) x += y;
    }
    if (lane == 63) swsum[wv] = x;
    __syncthreads();
    unsigned woff = 0;
    for (int w = 0; w < wv; ++w) woff += swsum[w];
    unsigned run = woff + x - part;    // exclusive prefix (count in bins above)
    #pragma unroll
    for (int e = 0; e < per; ++e) {
        unsigned c = vals[e];
        if (run < need && run + c >= need) {
            s_res[0] = (unsigned)(NB - 1 - (tid * per + e));
            s_res[1] = run;
        }
        run += c;
    }
    __syncthreads();
}

// ============ FAST PATH ============

// K1a: 512 blocks (b*64 + chunk). Per-chunk LDS hist -> global hist[b][lvl].
__global__ __launch_bounds__(512) void topk_hist(const float* __restrict__ obj,
                                                 unsigned* __restrict__ hist) {
    int blk = blockIdx.x;
    int b = blk >> 6, c = blk & 63;
    int lvl = c < 48 ? 0 : c < 60 ? 1 : c < 63 ? 2 : 3;
    const float4* src = (const float4*)(obj + (size_t)b * A_TOTAL + (size_t)c * 4096);
    int n4c = (c == 63) ? 768 : 1024;
    __shared__ unsigned h[2048];
    int tid = threadIdx.x;
    for (int i = tid; i < 2048; i += 512) h[i] = 0;
    __syncthreads();
    for (int i4 = tid; i4 < n4c; i4 += 512) {
        float4 v = src[i4];
        atomicAdd(&h[sortable(v.x) >> 21], 1u);
        atomicAdd(&h[sortable(v.y) >> 21], 1u);
        atomicAdd(&h[sortable(v.z) >> 21], 1u);
        atomicAdd(&h[sortable(v.w) >> 21], 1u);
    }
    __syncthreads();
    unsigned* gh = hist + ((size_t)(b * 4 + lvl) << 11);
    for (int i = tid; i < 2048; i += 512) {
        unsigned cc = h[i];
        if (cc) atomicAdd(&gh[i], cc);
    }
}

// K1b: 32 blocks (b,lvl). One data scan: >bin -> out; ==bin -> candidates;
// exact top-m of candidates via 3x13-bit radix select on 39-bit unique keys.
__global__ __launch_bounds__(512) void topk_select(const float* __restrict__ obj,
                                                   const unsigned* __restrict__ hist,
                                                   int* __restrict__ sel) {
    const int offs[4] = {0, 196608, 245760, 258048};
    const int ns[4]   = {196608, 49152, 12288, 3072};
    int b = blockIdx.x >> 2, lvl = blockIdx.x & 3;
    int off = offs[lvl], n = ns[lvl];
    const float4* src4 = (const float4*)(obj + (size_t)b * A_TOTAL + off);
    int n4 = n >> 2;
    __shared__ unsigned h[8192];
    __shared__ u64 cand[8192];
    __shared__ unsigned s_res[2];
    __shared__ unsigned swsum[8];
    __shared__ unsigned s_cnt, s_eq, s_c2;
    int tid = threadIdx.x;

    for (int i = tid; i < 2048; i += 512) h[i] = hist[((size_t)blockIdx.x << 11) + i];
    if (tid == 0) { s_cnt = 0; s_eq = 0; s_c2 = 0; }
    __syncthreads();
    radix_sel<2048>(h, K_PER_LVL, s_res, swsum);
    unsigned T1 = s_res[0], G1 = s_res[1];

    int* out = sel + (size_t)blockIdx.x * K_PER_LVL;
    for (int i4 = tid; i4 < n4; i4 += 512) {
        float4 v = src4[i4];
        float arr[4] = {v.x, v.y, v.z, v.w};
        #pragma unroll
        for (int c = 0; c < 4; ++c) {
            unsigned k = sortable(arr[c]);
            unsigned bin = k >> 21;
            int i = 4 * i4 + c;
            if (bin > T1) {
                out[atomicAdd(&s_cnt, 1u)] = off + i;
            } else if (bin == T1) {
                unsigned p = atomicAdd(&s_eq, 1u);
                if (p < 8192)
                    cand[p] = (((u64)(k & 0x1FFFFFu)) << 18)
                            | (u64)(0x3FFFFu - (unsigned)i);
            }
        }
    }
    __syncthreads();
    int E = (int)min(s_eq, 8192u);
    unsigned m = K_PER_LVL - G1;

    // pass A: bits 38:26
    for (int i = tid; i < 8192; i += 512) h[i] = 0;
    __syncthreads();
    for (int e = tid; e < E; e += 512) atomicAdd(&h[(unsigned)(cand[e] >> 26)], 1u);
    __syncthreads();
    radix_sel<8192>(h, m, s_res, swsum);
    unsigned TA = s_res[0], GA = s_res[1];
    // pass B: bits 25:13 among prefix TA
    for (int i = tid; i < 8192; i += 512) h[i] = 0;
    __syncthreads();
    for (int e = tid; e < E; e += 512) {
        u64 ck = cand[e];
        if ((unsigned)(ck >> 26) == TA) atomicAdd(&h[(unsigned)(ck >> 13) & 0x1FFFu], 1u);
    }
    __syncthreads();
    radix_sel<8192>(h, m - GA, s_res, swsum);
    unsigned TB = s_res[0], GB = s_res[1];
    // pass C: bits 12:0 among prefix (TA,TB)
    for (int i = tid; i < 8192; i += 512) h[i] = 0;
    __syncthreads();
    unsigned pref26 = (TA << 13) | TB;
    for (int e = tid; e < E; e += 512) {
        u64 ck = cand[e];
        if ((unsigned)(ck >> 13) == pref26) atomicAdd(&h[(unsigned)ck & 0x1FFFu], 1u);
    }
    __syncthreads();
    radix_sel<8192>(h, m - GA - GB, s_res, swsum);
    unsigned TC = s_res[0];
    u64 KSTAR = (((u64)TA) << 26) | (((u64)TB) << 13) | (u64)TC;
    for (int e = tid; e < E; e += 512) {
        u64 ck = cand[e];
        if (ck >= KSTAR) {
            unsigned p = atomicAdd(&s_c2, 1u);
            out[G1 + p] = off + (int)(0x3FFFFu - (unsigned)(ck & 0x3FFFFu));
        }
    }
}

// K2: per-image decode + bitonic sort + permute; store sorted SoA to ws.
__global__ __launch_bounds__(512) void decode_sort(const float* __restrict__ obj,
                                                   const float* __restrict__ deltas,
                                                   const float* __restrict__ anchors,
                                                   const int* __restrict__ sel,
                                                   float* __restrict__ gx1, float* __restrict__ gy1,
                                                   float* __restrict__ gx2, float* __restrict__ gy2,
                                                   float* __restrict__ gar, float* __restrict__ gsc,
                                                   unsigned char* __restrict__ glv,
                                                   int* __restrict__ gV) {
    int b = blockIdx.x;
    int tid = threadIdx.x;
    const int nth = 512;

    __shared__ u64 key[NSORT];
    __shared__ float bx1[NSORT], by1[NSORT], bx2[NSORT], by2[NSORT], bar[NSORT];
    __shared__ unsigned char blv[NSORT];
    __shared__ int sV;

    if (tid == 0) sV = K_TOTAL;

    for (int s = tid; s < NSORT; s += nth) {
        if (s < K_TOTAL) {
            int g = sel[(size_t)b * K_TOTAL + s];
            float score = obj[(size_t)b * A_TOTAL + g];
            float4 dl = *(const float4*)(deltas + ((size_t)b * A_TOTAL + g) * 4);
            float4 an = *(const float4*)(anchors + (size_t)g * 4);
            float wa = an.z - an.x, ha = an.w - an.y;
            float cxa = an.x + 0.5f * wa, cya = an.y + 0.5f * ha;
            float dw = fminf(dl.z, BBOX_CLIP), dh = fminf(dl.w, BBOX_CLIP);
            float cx = dl.x * wa + cxa, cy = dl.y * ha + cya;
            float w = expf(dw) * wa, h = expf(dh) * ha;
            float x1 = cx - 0.5f * w, y1 = cy - 0.5f * h;
            float x2 = cx + 0.5f * w, y2 = cy + 0.5f * h;
            x1 = fminf(fmaxf(x1, 0.f), 1024.f);
            y1 = fminf(fmaxf(y1, 0.f), 1024.f);
            x2 = fminf(fmaxf(x2, 0.f), 1024.f);
            y2 = fminf(fmaxf(y2, 0.f), 1024.f);
            bool valid = (x2 - x1 >= 0.001f) && (y2 - y1 >= 0.001f) && (score >= 0.f);
            float sm = valid ? score : NEGV;
            int lv = (g >= 258048) ? 3 : (g >= 245760) ? 2 : (g >= 196608) ? 1 : 0;
            float lo = (float)lv * 1025.0f;
            float xo1 = x1 + lo, yo1 = y1 + lo, xo2 = x2 + lo, yo2 = y2 + lo;
            bx1[s] = xo1; by1[s] = yo1; bx2[s] = xo2; by2[s] = yo2;
            bar[s] = (xo2 - xo1) * (yo2 - yo1);
            blv[s] = (unsigned char)lv;
            key[s] = ((u64)sortable(sm) << 32)
                   | ((u64)(0x3FFFFu - (unsigned)g) << 12)
                   | (unsigned)s;
        } else {
            bx1[s] = 0.f; by1[s] = 0.f; bx2[s] = 0.f; by2[s] = 0.f;
            bar[s] = 0.f; blv[s] = 0;
            key[s] = ((u64)sortable(NEGV) << 32) | (unsigned)s;
        }
    }
    __syncthreads();

    for (int k = 2; k <= NSORT; k <<= 1) {
        for (int j = k >> 1; j > 0; j >>= 1) {
            for (int i = tid; i < NSORT; i += nth) {
                int p = i ^ j;
                if (p > i) {
                    u64 a = key[i], c = key[p];
                    bool up = (i & k) == 0;
                    if (up ? (a < c) : (a > c)) { key[i] = c; key[p] = a; }
                }
            }
            __syncthreads();
        }
    }

    {
        float px1[8], py1[8], px2[8], py2[8], pa[8];
        unsigned char plv[8];
        #pragma unroll
        for (int e = 0; e < 8; ++e) {
            int i = tid * 8 + e;
            int slot = (int)(key[i] & 0xFFFull);
            px1[e] = bx1[slot]; py1[e] = by1[slot];
            px2[e] = bx2[slot]; py2[e] = by2[slot];
            pa[e] = bar[slot];  plv[e] = blv[slot];
            if (i < K_TOTAL && (unsigned)(key[i] >> 32) < 0x80000000u) atomicMin(&sV, i);
        }
        __syncthreads();
        #pragma unroll
        for (int e = 0; e < 8; ++e) {
            int i = tid * 8 + e;
            bx1[i] = px1[e]; by1[i] = py1[e];
            bx2[i] = px2[e]; by2[i] = py2[e];
            bar[i] = pa[e];  blv[i] = plv[e];
        }
    }
    __syncthreads();

    size_t base = (size_t)b * NSORT;
    for (int i = tid; i < NSORT; i += nth) {
        gx1[base + i] = bx1[i]; gy1[base + i] = by1[i];
        gx2[base + i] = bx2[i]; gy2[base + i] = by2[i];
        gar[base + i] = bar[i]; glv[base + i] = blv[i];
        gsc[base + i] = unsortable((unsigned)(key[i] >> 32));
    }
    if (tid == 0) gV[b] = sV;
}

// K3: build triangular suppression bit-matrix. Grid 256: b(3b) rc(2b) wg(3b).
__global__ __launch_bounds__(512) void build_mat(const float* __restrict__ gx1,
                                                 const float* __restrict__ gy1,
                                                 const float* __restrict__ gx2,
                                                 const float* __restrict__ gy2,
                                                 const float* __restrict__ gar,
                                                 const int* __restrict__ gV,
                                                 u64* __restrict__ mat) {
    int b = blockIdx.x >> 5, rc = (blockIdx.x >> 3) & 3, wg = blockIdx.x & 7;
    if (rc * 1024 >= wg * 512 + 512) return;   // all rows past all cols
    int V = gV[b];
    __shared__ float cx1[512], cy1[512], cx2[512], cy2[512], car[512];
    int tid = threadIdx.x;
    int j0 = wg * 512;
    size_t base = (size_t)b * NSORT;
    cx1[tid] = gx1[base + j0 + tid];
    cy1[tid] = gy1[base + j0 + tid];
    cx2[tid] = gx2[base + j0 + tid];
    cy2[tid] = gy2[base + j0 + tid];
    car[tid] = gar[base + j0 + tid];
    __syncthreads();

    #pragma unroll
    for (int r = 0; r < 2; ++r) {
        int i = rc * 1024 + r * 512 + tid;
        if (i >= V) continue;
        float ix1 = gx1[base + i], iy1 = gy1[base + i];
        float ix2 = gx2[base + i], iy2 = gy2[base + i], ia = gar[base + i];
        int wlo = wg * 8;
        int wi = i >> 6;
        if (wi > wlo) wlo = wi;
        for (int w = wlo; w < wg * 8 + 8; ++w) {
            u64 bits = 0;
            int jb = w * 64 - j0;
            for (int jj = 0; jj < 64; ++jj) {
                int j = w * 64 + jj;
                float lx = fmaxf(ix1, cx1[jb + jj]);
                float ly = fmaxf(iy1, cy1[jb + jj]);
                float rx = fminf(ix2, cx2[jb + jj]);
                float ry = fminf(iy2, cy2[jb + jj]);
                float wx = fmaxf(rx - lx, 0.f), wy = fmaxf(ry - ly, 0.f);
                float inter = wx * wy;
                float iou = inter / (ia + car[jb + jj] - inter + 1e-9f);
                bits |= ((u64)(iou > 0.7f && j > i)) << jj;
            }
            mat[((size_t)b << 18) | ((size_t)i << 6) | (unsigned)w] = bits;
        }
    }
}

// K4: per-image serial greedy resolve (1 wave, 16-deep row prefetch) + emit.
__global__ __launch_bounds__(512) void resolve_emit(const u64* __restrict__ mat,
                                                    const float* __restrict__ gx1,
                                                    const float* __restrict__ gy1,
                                                    const float* __restrict__ gx2,
                                                    const float* __restrict__ gy2,
                                                    const float* __restrict__ gsc,
                                                    const unsigned char* __restrict__ glv,
                                                    const int* __restrict__ gV,
                                                    float* __restrict__ out_boxes,
                                                    float* __restrict__ out_scores) {
    int b = blockIdx.x;
    int tid = threadIdx.x;
    int lane = tid & 63, wvi = tid >> 6;
    __shared__ unsigned short klist[POST_N];
    __shared__ int s_kc;
    int V = gV[b];

    if (wvi == 0) {
        const u64* M = mat + ((size_t)b << 18);
        u64 remv = 0;
        int kc = 0;
        u64 cur[16], nxt[16];
        #pragma unroll
        for (int e = 0; e < 16; ++e) cur[e] = M[((size_t)e << 6) + lane];
        for (int g = 0; g * 16 < V && kc < POST_N; ++g) {
            int gb = g * 16;
            #pragma unroll
            for (int e = 0; e < 16; ++e) {
                int i2 = gb + 16 + e;
                nxt[e] = (i2 < NSORT) ? M[((size_t)i2 << 6) + lane] : 0ull;
            }
            #pragma unroll
            for (int e = 0; e < 16; ++e) {
                int i = gb + e;
                if (i >= V || kc >= POST_N) break;
                int wi = i >> 6;
                u64 word = __shfl(remv, wi);
                if (!((word >> (i & 63)) & 1ull)) {
                    if (lane == 0) klist[kc] = (unsigned short)i;
                    kc++;
                    u64 row = (lane >= wi) ? cur[e] : 0ull;
                    remv |= row;
                }
            }
            #pragma unroll
            for (int e = 0; e < 16; ++e) cur[e] = nxt[e];
        }
        if (lane == 0) s_kc = kc;
    }
    __syncthreads();
    int kc = s_kc;

    float* ob = out_boxes + (size_t)b * POST_N * 4;
    float* os = out_scores + (size_t)b * POST_N;
    for (int q = tid; q < POST_N; q += 512) {
        ob[4 * q + 0] = 0.f; ob[4 * q + 1] = 0.f;
        ob[4 * q + 2] = 0.f; ob[4 * q + 3] = 0.f;
        os[q] = 0.f;
    }
    __syncthreads();
    size_t base = (size_t)b * NSORT;
    for (int p = tid; p < kc; p += 512) {
        int i = klist[p];
        float lo = (float)glv[base + i] * 1025.0f;
        ob[4 * p + 0] = gx1[base + i] - lo;
        ob[4 * p + 1] = gy1[base + i] - lo;
        ob[4 * p + 2] = gx2[base + i] - lo;
        ob[4 * p + 3] = gy2[base + i] - lo;
        os[p] = gsc[base + i];
    }
}

// ============ FALLBACK PATH (round-2, needs only 128 KB ws) ============

__global__ __launch_bounds__(512) void topk_kernel(const float* __restrict__ obj,
                                                   int* __restrict__ sel) {
    const int offs[4] = {0, 196608, 245760, 258048};
    const int ns[4]   = {196608, 49152, 12288, 3072};
    int blk = blockIdx.x;
    int b = blk >> 2, lvl = blk & 3;
    int off = offs[lvl], n = ns[lvl];
    const float* src = obj + (size_t)b * A_TOTAL + off;
    const float4* src4 = (const float4*)src;
    int n4 = n >> 2;

    __shared__ unsigned whist[8 * 2048];
    __shared__ int eqbuf[2048];
    __shared__ unsigned s_res[2];
    __shared__ unsigned swsum[8];
    __shared__ unsigned s_cnt, s_eq;
    int tid = threadIdx.x;
    int wv = tid >> 6;

    for (int i = tid; i < 8 * 2048; i += 512) whist[i] = 0;
    if (tid == 0) { s_cnt = 0; s_eq = 0; }
    __syncthreads();

    unsigned* myh = whist + wv * 2048;
    for (int i = tid; i < n4; i += 512) {
        float4 v = src4[i];
        atomicAdd(&myh[sortable(v.x) >> 21], 1u);
        atomicAdd(&myh[sortable(v.y) >> 21], 1u);
        atomicAdd(&myh[sortable(v.z) >> 21], 1u);
        atomicAdd(&myh[sortable(v.w) >> 21], 1u);
    }
    __syncthreads();
    for (int bin = tid; bin < 2048; bin += 512) {
        unsigned s = 0;
        #pragma unroll
        for (int w = 0; w < 8; ++w) s += whist[w * 2048 + bin];
        whist[bin] = s;
    }
    __syncthreads();
    radix_sel<2048>(whist, K_PER_LVL, s_res, swsum);
    unsigned T1 = s_res[0], G1 = s_res[1];

    for (int i = tid; i < 2048; i += 512) whist[i] = 0;
    __syncthreads();
    for (int i = tid; i < n4; i += 512) {
        float4 v = src4[i];
        unsigned k;
        k = sortable(v.x); if ((k >> 21) == T1) atomicAdd(&whist[(k >> 10) & 0x7FFu], 1u);
        k = sortable(v.y); if ((k >> 21) == T1) atomicAdd(&whist[(k >> 10) & 0x7FFu], 1u);
        k = sortable(v.z); if ((k >> 21) == T1) atomicAdd(&whist[(k >> 10) & 0x7FFu], 1u);
        k = sortable(v.w); if ((k >> 21) == T1) atomicAdd(&whist[(k >> 10) & 0x7FFu], 1u);
    }
    __syncthreads();
    radix_sel<2048>(whist, K_PER_LVL - G1, s_res, swsum);
    unsigned T2 = s_res[0], G2 = s_res[1];
    unsigned pref21 = (T1 << 11) | T2;

    for (int i = tid; i < 1024; i += 512) whist[i] = 0;
    __syncthreads();
    for (int i = tid; i < n4; i += 512) {
        float4 v = src4[i];
        unsigned k;
        k = sortable(v.x); if ((k >> 10) == pref21) atomicAdd(&whist[k & 0x3FFu], 1u);
        k = sortable(v.y); if ((k >> 10) == pref21) atomicAdd(&whist[k & 0x3FFu], 1u);
        k = sortable(v.z); if ((k >> 10) == pref21) atomicAdd(&whist[k & 0x3FFu], 1u);
        k = sortable(v.w); if ((k >> 10) == pref21) atomicAdd(&whist[k & 0x3FFu], 1u);
    }
    __syncthreads();
    radix_sel<1024>(whist, K_PER_LVL - G1 - G2, s_res, swsum);
    unsigned T3 = s_res[0], G3 = s_res[1];
    unsigned Kstar = (pref21 << 10) | T3;
    unsigned Gtot = G1 + G2 + G3;

    int* out = sel + (size_t)(b * 4 + lvl) * K_PER_LVL;
    for (int i4 = tid; i4 < n4; i4 += 512) {
        float4 v = src4[i4];
        float arr[4] = {v.x, v.y, v.z, v.w};
        #pragma unroll
        for (int c = 0; c < 4; ++c) {
            unsigned k = sortable(arr[c]);
            int i = 4 * i4 + c;
            if (k > Kstar) {
                unsigned p = atomicAdd(&s_cnt, 1u);
                out[p] = off + i;
            } else if (k == Kstar) {
                unsigned p = atomicAdd(&s_eq, 1u);
                if (p < 2048) eqbuf[p] = i;
            }
        }
    }
    __syncthreads();
    if (tid == 0) {
        int m = K_PER_LVL - (int)Gtot;
        int E = (int)min(s_eq, 2048u);
        int bse = (int)Gtot;
        int last = -1;
        for (int r = 0; r < m; ++r) {
            int best = 0x7FFFFFFF;
            for (int e = 0; e < E; ++e) {
                int v = eqbuf[e];
                if (v > last && v < best) best = v;
            }
            out[bse + r] = off + best;
            last = best;
        }
    }
}

__global__ __launch_bounds__(512) void nms_kernel(const float* __restrict__ obj,
                                                  const float* __restrict__ deltas,
                                                  const float* __restrict__ anchors,
                                                  const int* __restrict__ sel,
                                                  float* __restrict__ out_boxes,
                                                  float* __restrict__ out_scores) {
    int b = blockIdx.x;
    int tid = threadIdx.x;
    const int nth = 512;
    int lane = tid & 63, wvi = tid >> 6;

    __shared__ u64 key[NSORT];
    __shared__ float bx1[NSORT], by1[NSORT], bx2[NSORT], by2[NSORT], bar[NSORT];
    __shared__ unsigned char blv[NSORT];
    __shared__ unsigned char rm[NSORT];
    __shared__ u64 srow[64];
    __shared__ u64 s_alive;
    __shared__ int sV;
    __shared__ unsigned swsum[8];

    if (tid == 0) sV = K_TOTAL;

    for (int s = tid; s < NSORT; s += nth) {
        if (s < K_TOTAL) {
            int g = sel[(size_t)b * K_TOTAL + s];
            float score = obj[(size_t)b * A_TOTAL + g];
            float4 dl = *(const float4*)(deltas + ((size_t)b * A_TOTAL + g) * 4);
            float4 an = *(const float4*)(anchors + (size_t)g * 4);
            float wa = an.z - an.x, ha = an.w - an.y;
            float cxa = an.x + 0.5f * wa, cya = an.y + 0.5f * ha;
            float dw = fminf(dl.z, BBOX_CLIP), dh = fminf(dl.w, BBOX_CLIP);
            float cx = dl.x * wa + cxa, cy = dl.y * ha + cya;
            float w = expf(dw) * wa, h = expf(dh) * ha;
            float x1 = cx - 0.5f * w, y1 = cy - 0.5f * h;
            float x2 = cx + 0.5f * w, y2 = cy + 0.5f * h;
            x1 = fminf(fmaxf(x1, 0.f), 1024.f);
            y1 = fminf(fmaxf(y1, 0.f), 1024.f);
            x2 = fminf(fmaxf(x2, 0.f), 1024.f);
            y2 = fminf(fmaxf(y2, 0.f), 1024.f);
            bool valid = (x2 - x1 >= 0.001f) && (y2 - y1 >= 0.001f) && (score >= 0.f);
            float sm = valid ? score : NEGV;
            int lv = (g >= 258048) ? 3 : (g >= 245760) ? 2 : (g >= 196608) ? 1 : 0;
            float lo = (float)lv * 1025.0f;
            float xo1 = x1 + lo, yo1 = y1 + lo, xo2 = x2 + lo, yo2 = y2 + lo;
            bx1[s] = xo1; by1[s] = yo1; bx2[s] = xo2; by2[s] = yo2;
            bar[s] = (xo2 - xo1) * (yo2 - yo1);
            blv[s] = (unsigned char)lv;
            key[s] = ((u64)sortable(sm) << 32)
                   | ((u64)(0x3FFFFu - (unsigned)g) << 12)
                   | (unsigned)s;
        } else {
            bx1[s] = 0.f; by1[s] = 0.f; bx2[s] = 0.f; by2[s] = 0.f;
            bar[s] = 0.f; blv[s] = 0;
            key[s] = ((u64)sortable(NEGV) << 32) | (unsigned)s;
        }
    }
    __syncthreads();

    for (int k = 2; k <= NSORT; k <<= 1) {
        for (int j = k >> 1; j > 0; j >>= 1) {
            for (int i = tid; i < NSORT; i += nth) {
                int p = i ^ j;
                if (p > i) {
                    u64 a = key[i], c = key[p];
                    bool up = (i & k) == 0;
                    if (up ? (a < c) : (a > c)) { key[i] = c; key[p] = a; }
                }
            }
            __syncthreads();
        }
    }

    {
        float px1[8], py1[8], px2[8], py2[8], pa[8];
        unsigned char plv[8];
        #pragma unroll
        for (int e = 0; e < 8; ++e) {
            int i = tid * 8 + e;
            int slot = (int)(key[i] & 0xFFFull);
            px1[e] = bx1[slot]; py1[e] = by1[slot];
            px2[e] = bx2[slot]; py2[e] = by2[slot];
            pa[e] = bar[slot];  plv[e] = blv[slot];
            if (i < K_TOTAL && (unsigned)(key[i] >> 32) < 0x80000000u) atomicMin(&sV, i);
        }
        __syncthreads();
        #pragma unroll
        for (int e = 0; e < 8; ++e) {
            int i = tid * 8 + e;
            bx1[i] = px1[e]; by1[i] = py1[e];
            bx2[i] = px2[e]; by2[i] = py2[e];
            bar[i] = pa[e];  blv[i] = plv[e];
            rm[i] = 0;
        }
    }
    __syncthreads();
    int V = sV;

    int nchunk = (V + 63) >> 6;
    int kept_total = 0;
    for (int c = 0; c < nchunk; ++c) {
        int base = c << 6;
        int j = base + lane;
        bool jin = j < V;
        float jx1 = bx1[j], jy1 = by1[j], jx2 = bx2[j], jy2 = by2[j], ja = bar[j];

        #pragma unroll
        for (int kk = 0; kk < 8; ++kk) {
            int k = (wvi << 3) + kk;
            float kx1 = bx1[base + k], ky1 = by1[base + k];
            float kx2 = bx2[base + k], ky2 = by2[base + k], ka = bar[base + k];
            bool sup = false;
            if (jin && lane > k) {
                float lx = fmaxf(kx1, jx1), ly = fmaxf(ky1, jy1);
                float rx = fminf(kx2, jx2), ry = fminf(ky2, jy2);
                float wx = fmaxf(rx - lx, 0.f), wy = fmaxf(ry - ly, 0.f);
                float inter = wx * wy;
                float iou = inter / (ka + ja - inter + 1e-9f);
                sup = iou > 0.7f;
            }
            u64 r = __ballot(sup);
            if (lane == 0) srow[k] = r;
        }
        __syncthreads();

        if (wvi == 0) {
            u64 row = srow[lane];
            bool a0 = jin && (rm[j] == 0);
            u64 alive = __ballot(a0);
            u64 m = alive;
            while (m) {
                int k = __ffsll((long long)m) - 1;
                u64 r = __shfl(row, k);
                alive &= ~r;
                m &= alive;
                m &= ~(1ULL << k);
            }
            if (jin && a0 && !((alive >> lane) & 1)) rm[j] = 1;
            if (lane == 0) s_alive = alive;
        }
        __syncthreads();

        u64 aliveC = s_alive;
        kept_total += __popcll(aliveC);
        if (kept_total >= POST_N) break;

        for (int i = base + 64 + tid; i < V; i += nth) {
            if (rm[i]) continue;
            float ix1 = bx1[i], iy1 = by1[i], ix2 = bx2[i], iy2 = by2[i], ia = bar[i];
            u64 mm = aliveC;
            bool dead = false;
            while (mm) {
                int k = __ffsll((long long)mm) - 1; mm &= mm - 1;
                float kx1 = bx1[base + k], ky1 = by1[base + k];
                float kx2 = bx2[base + k], ky2 = by2[base + k], ka = bar[base + k];
                float lx = fmaxf(kx1, ix1), ly = fmaxf(ky1, iy1);
                float rx = fminf(kx2, ix2), ry = fminf(ky2, iy2);
                float wx = fmaxf(rx - lx, 0.f), wy = fmaxf(ry - ly, 0.f);
                float inter = wx * wy;
                float iou = inter / (ka + ia - inter + 1e-9f);
                if (iou > 0.7f) { dead = true; break; }
            }
            if (dead) rm[i] = 1;
        }
        __syncthreads();
    }
    __syncthreads();

    float* ob = out_boxes + (size_t)b * POST_N * 4;
    float* os = out_scores + (size_t)b * POST_N;
    for (int q = tid; q < POST_N; q += nth) {
        ob[4 * q + 0] = 0.f; ob[4 * q + 1] = 0.f;
        ob[4 * q + 2] = 0.f; ob[4 * q + 3] = 0.f;
        os[q] = 0.f;
    }
    __syncthreads();

    int cnt = 0;
    unsigned char kf[8];
    #pragma unroll
    for (int e = 0; e < 8; ++e) {
        int i = tid * 8 + e;
        int f = (i < V && rm[i] == 0) ? 1 : 0;
        kf[e] = (unsigned char)f; cnt += f;
    }
    int x = cnt;
    #pragma unroll
    for (int d = 1; d < 64; d <<= 1) {
        int y = __shfl_up(x, d);
        if (lane >= d) x += y;
    }
    if (lane == 63) swsum[wvi] = (unsigned)x;
    __syncthreads();
    int woff = 0;
    for (int w = 0; w < wvi; ++w) woff += (int)swsum[w];
    int p = woff + x - cnt;
    #pragma unroll
    for (int e = 0; e < 8; ++e) {
        if (kf[e]) {
            if (p < POST_N) {
                int i = tid * 8 + e;
                float lo = (float)blv[i] * 1025.0f;
                ob[4 * p + 0] = bx1[i] - lo;
                ob[4 * p + 1] = by1[i] - lo;
                ob[4 * p + 2] = bx2[i] - lo;
                ob[4 * p + 3] = by2[i] - lo;
                os[p] = unsortable((unsigned)(key[i] >> 32));
            }
            ++p;
        }
    }
}

extern "C" void kernel_launch(void* const* d_in, const int* in_sizes, int n_in,
                              void* d_out, int out_size, void* d_ws, size_t ws_size,
                              hipStream_t stream) {
    const float* obj     = (const float*)d_in[0];
    const float* deltas  = (const float*)d_in[1];
    const float* anchors = (const float*)d_in[2];
    float* out_boxes  = (float*)d_out;
    float* out_scores = (float*)d_out + B_BATCH * POST_N * 4;
    char* ws = (char*)d_ws;

    const size_t O_SEL  = 0;        // int[8][4000]           = 128000
    const size_t O_HIST = 131072;   // u32[32][2048]          = 262144
    const size_t O_BX1  = 393216;   // f32[8][4096] each ↓    = 131072
    const size_t O_BY1  = 524288;
    const size_t O_BX2  = 655360;
    const size_t O_BY2  = 786432;
    const size_t O_BAR  = 917504;
    const size_t O_BSC  = 1048576;
    const size_t O_BLV  = 1179648;  // u8[8][4096]            = 32768
    const size_t O_BV   = 1212416;  // int[8]
    const size_t O_MAT  = 2097152;  // u64[8][4096][64]       = 16777216
    const size_t NEED   = O_MAT + (size_t)16777216;

    if (ws_size >= NEED) {
        hipMemsetAsync(ws + O_HIST, 0, 262144, stream);
        topk_hist<<<512, 512, 0, stream>>>(obj, (unsigned*)(ws + O_HIST));
        topk_select<<<32, 512, 0, stream>>>(obj, (const unsigned*)(ws + O_HIST),
                                            (int*)(ws + O_SEL));
        decode_sort<<<8, 512, 0, stream>>>(obj, deltas, anchors, (const int*)(ws + O_SEL),
                                           (float*)(ws + O_BX1), (float*)(ws + O_BY1),
                                           (float*)(ws + O_BX2), (float*)(ws + O_BY2),
                                           (float*)(ws + O_BAR), (float*)(ws + O_BSC),
                                           (unsigned char*)(ws + O_BLV), (int*)(ws + O_BV));
        build_mat<<<256, 512, 0, stream>>>((const float*)(ws + O_BX1), (const float*)(ws + O_BY1),
                                           (const float*)(ws + O_BX2), (const float*)(ws + O_BY2),
                                           (const float*)(ws + O_BAR), (const int*)(ws + O_BV),
                                           (u64*)(ws + O_MAT));
        resolve_emit<<<8, 512, 0, stream>>>((const u64*)(ws + O_MAT),
                                            (const float*)(ws + O_BX1), (const float*)(ws + O_BY1),
                                            (const float*)(ws + O_BX2), (const float*)(ws + O_BY2),
                                            (const float*)(ws + O_BSC),
                                            (const unsigned char*)(ws + O_BLV),
                                            (const int*)(ws + O_BV),
                                            out_boxes, out_scores);
    } else {
        topk_kernel<<<32, 512, 0, stream>>>(obj, (int*)ws);
        nms_kernel<<<B_BATCH, 512, 0, stream>>>(obj, deltas, anchors, (const int*)ws,
                                                out_boxes, out_scores);
    }
}

// Round 4
// 429.672 us; speedup vs baseline: 10.4928x; 1.0679x over previous
//
#include <hip/hip_runtime.h>
#include <math.h>

#define A_TOTAL 261120
#define B_BATCH 8
#define K_PER_LVL 1000
#define K_TOTAL 4000
#define NSORT 4096
#define POST_N 1000
#define NEGV -1e30f
#define BBOX_CLIP 4.135166556742356f

typedef unsigned long long u64;

__device__ __forceinline__ unsigned sortable(float f) {
    unsigned u = __float_as_uint(f);
    return (u & 0x80000000u) ? ~u : (u | 0x80000000u);
}

__device__ __forceinline__ float unsortable(unsigned u) {
    return (u & 0x80000000u) ? __uint_as_float(u & 0x7FFFFFFFu) : __uint_as_float(~u);
}

// Parallel "find threshold bin from top" over hist[NB]; all 512 threads call.
// Result: s_res[0]=T (bin), s_res[1]=G (count strictly above bin T).
template<int NB>
__device__ __forceinline__ void radix_sel(unsigned* hist, unsigned need,
                                          unsigned* s_res, unsigned* swsum) {
    const int per = NB >> 9;
    int tid = threadIdx.x;
    unsigned vals[per];
    unsigned part = 0;
    #pragma unroll
    for (int e = 0; e < per; ++e) {
        unsigned v = hist[NB - 1 - (tid * per + e)];   // high bins first
        vals[e] = v; part += v;
    }
    int lane = tid & 63, wv = tid >> 6;
    unsigned x = part;
    #pragma unroll
    for (int d = 1; d < 64; d <<= 1) {
        unsigned y = __shfl_up(x, d);
        if (lane >= d) x += y;
    }
    if (lane == 63) swsum[wv] = x;
    __syncthreads();
    unsigned woff = 0;
    for (int w = 0; w < wv; ++w) woff += swsum[w];
    unsigned run = woff + x - part;    // exclusive prefix (count in bins above)
    #pragma unroll
    for (int e = 0; e < per; ++e) {
        unsigned c = vals[e];
        if (run < need && run + c >= need) {
            s_res[0] = (unsigned)(NB - 1 - (tid * per + e));
            s_res[1] = run;
        }
        run += c;
    }
    __syncthreads();
}

// ============ FAST PATH ============

// K1a: 512 blocks (b*64 + chunk). Per-chunk LDS hist -> global hist[b][lvl].
__global__ __launch_bounds__(512) void topk_hist(const float* __restrict__ obj,
                                                 unsigned* __restrict__ hist) {
    int blk = blockIdx.x;
    int b = blk >> 6, c = blk & 63;
    int lvl = c < 48 ? 0 : c < 60 ? 1 : c < 63 ? 2 : 3;
    const float4* src = (const float4*)(obj + (size_t)b * A_TOTAL + (size_t)c * 4096);
    int n4c = (c == 63) ? 768 : 1024;
    __shared__ unsigned h[2048];
    int tid = threadIdx.x;
    for (int i = tid; i < 2048; i += 512) h[i] = 0;
    __syncthreads();
    for (int i4 = tid; i4 < n4c; i4 += 512) {
        float4 v = src[i4];
        atomicAdd(&h[sortable(v.x) >> 21], 1u);
        atomicAdd(&h[sortable(v.y) >> 21], 1u);
        atomicAdd(&h[sortable(v.z) >> 21], 1u);
        atomicAdd(&h[sortable(v.w) >> 21], 1u);
    }
    __syncthreads();
    unsigned* gh = hist + ((size_t)(b * 4 + lvl) << 11);
    for (int i = tid; i < 2048; i += 512) {
        unsigned cc = h[i];
        if (cc) atomicAdd(&gh[i], cc);
    }
}

// K1b: 32 blocks (b,lvl). One data scan: >bin -> out; ==bin -> candidates;
// exact top-m of candidates via 3x13-bit radix select on 39-bit unique keys.
__global__ __launch_bounds__(512) void topk_select(const float* __restrict__ obj,
                                                   const unsigned* __restrict__ hist,
                                                   int* __restrict__ sel) {
    const int offs[4] = {0, 196608, 245760, 258048};
    const int ns[4]   = {196608, 49152, 12288, 3072};
    int b = blockIdx.x >> 2, lvl = blockIdx.x & 3;
    int off = offs[lvl], n = ns[lvl];
    const float4* src4 = (const float4*)(obj + (size_t)b * A_TOTAL + off);
    int n4 = n >> 2;
    __shared__ unsigned h[8192];
    __shared__ u64 cand[8192];
    __shared__ unsigned s_res[2];
    __shared__ unsigned swsum[8];
    __shared__ unsigned s_cnt, s_eq, s_c2;
    int tid = threadIdx.x;

    for (int i = tid; i < 2048; i += 512) h[i] = hist[((size_t)blockIdx.x << 11) + i];
    if (tid == 0) { s_cnt = 0; s_eq = 0; s_c2 = 0; }
    __syncthreads();
    radix_sel<2048>(h, K_PER_LVL, s_res, swsum);
    unsigned T1 = s_res[0], G1 = s_res[1];

    int* out = sel + (size_t)blockIdx.x * K_PER_LVL;
    for (int i4 = tid; i4 < n4; i4 += 512) {
        float4 v = src4[i4];
        float arr[4] = {v.x, v.y, v.z, v.w};
        #pragma unroll
        for (int c = 0; c < 4; ++c) {
            unsigned k = sortable(arr[c]);
            unsigned bin = k >> 21;
            int i = 4 * i4 + c;
            if (bin > T1) {
                out[atomicAdd(&s_cnt, 1u)] = off + i;
            } else if (bin == T1) {
                unsigned p = atomicAdd(&s_eq, 1u);
                if (p < 8192)
                    cand[p] = (((u64)(k & 0x1FFFFFu)) << 18)
                            | (u64)(0x3FFFFu - (unsigned)i);
            }
        }
    }
    __syncthreads();
    int E = (int)min(s_eq, 8192u);
    unsigned m = K_PER_LVL - G1;

    // pass A: bits 38:26
    for (int i = tid; i < 8192; i += 512) h[i] = 0;
    __syncthreads();
    for (int e = tid; e < E; e += 512) atomicAdd(&h[(unsigned)(cand[e] >> 26)], 1u);
    __syncthreads();
    radix_sel<8192>(h, m, s_res, swsum);
    unsigned TA = s_res[0], GA = s_res[1];
    // pass B: bits 25:13 among prefix TA
    for (int i = tid; i < 8192; i += 512) h[i] = 0;
    __syncthreads();
    for (int e = tid; e < E; e += 512) {
        u64 ck = cand[e];
        if ((unsigned)(ck >> 26) == TA) atomicAdd(&h[(unsigned)(ck >> 13) & 0x1FFFu], 1u);
    }
    __syncthreads();
    radix_sel<8192>(h, m - GA, s_res, swsum);
    unsigned TB = s_res[0], GB = s_res[1];
    // pass C: bits 12:0 among prefix (TA,TB)
    for (int i = tid; i < 8192; i += 512) h[i] = 0;
    __syncthreads();
    unsigned pref26 = (TA << 13) | TB;
    for (int e = tid; e < E; e += 512) {
        u64 ck = cand[e];
        if ((unsigned)(ck >> 13) == pref26) atomicAdd(&h[(unsigned)ck & 0x1FFFu], 1u);
    }
    __syncthreads();
    radix_sel<8192>(h, m - GA - GB, s_res, swsum);
    unsigned TC = s_res[0];
    u64 KSTAR = (((u64)TA) << 26) | (((u64)TB) << 13) | (u64)TC;
    for (int e = tid; e < E; e += 512) {
        u64 ck = cand[e];
        if (ck >= KSTAR) {
            unsigned p = atomicAdd(&s_c2, 1u);
            out[G1 + p] = off + (int)(0x3FFFFu - (unsigned)(ck & 0x3FFFFu));
        }
    }
}

// K2: per-image decode + bitonic sort + permute; store sorted SoA to ws.
__global__ __launch_bounds__(512) void decode_sort(const float* __restrict__ obj,
                                                   const float* __restrict__ deltas,
                                                   const float* __restrict__ anchors,
                                                   const int* __restrict__ sel,
                                                   float* __restrict__ gx1, float* __restrict__ gy1,
                                                   float* __restrict__ gx2, float* __restrict__ gy2,
                                                   float* __restrict__ gar, float* __restrict__ gsc,
                                                   unsigned char* __restrict__ glv,
                                                   int* __restrict__ gV) {
    int b = blockIdx.x;
    int tid = threadIdx.x;
    const int nth = 512;

    __shared__ u64 key[NSORT];
    __shared__ float bx1[NSORT], by1[NSORT], bx2[NSORT], by2[NSORT], bar[NSORT];
    __shared__ unsigned char blv[NSORT];
    __shared__ int sV;

    if (tid == 0) sV = K_TOTAL;

    for (int s = tid; s < NSORT; s += nth) {
        if (s < K_TOTAL) {
            int g = sel[(size_t)b * K_TOTAL + s];
            float score = obj[(size_t)b * A_TOTAL + g];
            float4 dl = *(const float4*)(deltas + ((size_t)b * A_TOTAL + g) * 4);
            float4 an = *(const float4*)(anchors + (size_t)g * 4);
            float wa = an.z - an.x, ha = an.w - an.y;
            float cxa = an.x + 0.5f * wa, cya = an.y + 0.5f * ha;
            float dw = fminf(dl.z, BBOX_CLIP), dh = fminf(dl.w, BBOX_CLIP);
            float cx = dl.x * wa + cxa, cy = dl.y * ha + cya;
            float w = expf(dw) * wa, h = expf(dh) * ha;
            float x1 = cx - 0.5f * w, y1 = cy - 0.5f * h;
            float x2 = cx + 0.5f * w, y2 = cy + 0.5f * h;
            x1 = fminf(fmaxf(x1, 0.f), 1024.f);
            y1 = fminf(fmaxf(y1, 0.f), 1024.f);
            x2 = fminf(fmaxf(x2, 0.f), 1024.f);
            y2 = fminf(fmaxf(y2, 0.f), 1024.f);
            bool valid = (x2 - x1 >= 0.001f) && (y2 - y1 >= 0.001f) && (score >= 0.f);
            float sm = valid ? score : NEGV;
            int lv = (g >= 258048) ? 3 : (g >= 245760) ? 2 : (g >= 196608) ? 1 : 0;
            float lo = (float)lv * 1025.0f;
            float xo1 = x1 + lo, yo1 = y1 + lo, xo2 = x2 + lo, yo2 = y2 + lo;
            bx1[s] = xo1; by1[s] = yo1; bx2[s] = xo2; by2[s] = yo2;
            bar[s] = (xo2 - xo1) * (yo2 - yo1);
            blv[s] = (unsigned char)lv;
            key[s] = ((u64)sortable(sm) << 32)
                   | ((u64)(0x3FFFFu - (unsigned)g) << 12)
                   | (unsigned)s;
        } else {
            bx1[s] = 0.f; by1[s] = 0.f; bx2[s] = 0.f; by2[s] = 0.f;
            bar[s] = 0.f; blv[s] = 0;
            key[s] = ((u64)sortable(NEGV) << 32) | (unsigned)s;
        }
    }
    __syncthreads();

    for (int k = 2; k <= NSORT; k <<= 1) {
        for (int j = k >> 1; j > 0; j >>= 1) {
            for (int i = tid; i < NSORT; i += nth) {
                int p = i ^ j;
                if (p > i) {
                    u64 a = key[i], c = key[p];
                    bool up = (i & k) == 0;
                    if (up ? (a < c) : (a > c)) { key[i] = c; key[p] = a; }
                }
            }
            __syncthreads();
        }
    }

    {
        float px1[8], py1[8], px2[8], py2[8], pa[8];
        unsigned char plv[8];
        #pragma unroll
        for (int e = 0; e < 8; ++e) {
            int i = tid * 8 + e;
            int slot = (int)(key[i] & 0xFFFull);
            px1[e] = bx1[slot]; py1[e] = by1[slot];
            px2[e] = bx2[slot]; py2[e] = by2[slot];
            pa[e] = bar[slot];  plv[e] = blv[slot];
            if (i < K_TOTAL && (unsigned)(key[i] >> 32) < 0x80000000u) atomicMin(&sV, i);
        }
        __syncthreads();
        #pragma unroll
        for (int e = 0; e < 8; ++e) {
            int i = tid * 8 + e;
            bx1[i] = px1[e]; by1[i] = py1[e];
            bx2[i] = px2[e]; by2[i] = py2[e];
            bar[i] = pa[e];  blv[i] = plv[e];
        }
    }
    __syncthreads();

    size_t base = (size_t)b * NSORT;
    for (int i = tid; i < NSORT; i += nth) {
        gx1[base + i] = bx1[i]; gy1[base + i] = by1[i];
        gx2[base + i] = bx2[i]; gy2[base + i] = by2[i];
        gar[base + i] = bar[i]; glv[base + i] = blv[i];
        gsc[base + i] = unsortable((unsigned)(key[i] >> 32));
    }
    if (tid == 0) gV[b] = sV;
}

// K3: build triangular suppression bit-matrix, one IoU per lane, ballot per word.
// Grid 512: blockIdx = b*64 + rb (64-row tile). 8 waves hold column strips in regs.
__global__ __launch_bounds__(512) void build_mat(const float* __restrict__ gx1,
                                                 const float* __restrict__ gy1,
                                                 const float* __restrict__ gx2,
                                                 const float* __restrict__ gy2,
                                                 const float* __restrict__ gar,
                                                 const int* __restrict__ gV,
                                                 u64* __restrict__ mat) {
    int b = blockIdx.x >> 6, rb = blockIdx.x & 63;
    int V = gV[b];
    int i0 = rb << 6;
    if (i0 >= V) return;
    int tid = threadIdx.x, lane = tid & 63, wvi = tid >> 6;
    size_t base = (size_t)b * NSORT;

    __shared__ float rx1[64], ry1[64], rx2[64], ry2[64], rar[64];
    __shared__ u64 tile[64][64];

    if (tid < 64) {
        rx1[tid] = gx1[base + i0 + tid];
        ry1[tid] = gy1[base + i0 + tid];
        rx2[tid] = gx2[base + i0 + tid];
        ry2[tid] = gy2[base + i0 + tid];
        rar[tid] = gar[base + i0 + tid];
    }

    // wave wvi owns words w = rb+wvi, rb+wvi+8, ... (lane = column within word)
    float c1[8], c2[8], c3[8], c4[8], ca[8];
    int w0 = rb + wvi;
    #pragma unroll
    for (int s = 0; s < 8; ++s) {
        int w = w0 + (s << 3);
        if (w < 64) {
            int j = (w << 6) + lane;
            c1[s] = gx1[base + j]; c2[s] = gy1[base + j];
            c3[s] = gx2[base + j]; c4[s] = gy2[base + j];
            ca[s] = gar[base + j];
        }
    }
    __syncthreads();

    int rmax = min(64, V - i0);
    for (int r = 0; r < rmax; ++r) {
        int i = i0 + r;
        float ix1 = rx1[r], iy1 = ry1[r], ix2 = rx2[r], iy2 = ry2[r], ia = rar[r];
        #pragma unroll
        for (int s = 0; s < 8; ++s) {
            int w = w0 + (s << 3);
            if (w < 64) {
                float lx = fmaxf(ix1, c1[s]);
                float ly = fmaxf(iy1, c2[s]);
                float rx = fminf(ix2, c3[s]);
                float ry = fminf(iy2, c4[s]);
                float wx = fmaxf(rx - lx, 0.f), wy = fmaxf(ry - ly, 0.f);
                float inter = wx * wy;
                float iou = inter / (ia + ca[s] - inter + 1e-9f);
                int j = (w << 6) + lane;
                u64 bits = __ballot(iou > 0.7f && j > i);
                if (lane == 0) tile[r][w] = bits;
            }
        }
    }
    __syncthreads();

    // contiguous 32 KB store (words w<rb / rows>=rmax are garbage; resolve masks them)
    u64* dst = mat + (((size_t)b << 18) | ((size_t)i0 << 6));
    const ulonglong2* s2 = (const ulonglong2*)&tile[0][0];
    ulonglong2* d2 = (ulonglong2*)dst;
    for (int q = tid; q < 2048; q += 512) d2[q] = s2[q];
}

// K4: per-image serial greedy resolve (1 wave, 16-deep row prefetch) + emit.
__global__ __launch_bounds__(512) void resolve_emit(const u64* __restrict__ mat,
                                                    const float* __restrict__ gx1,
                                                    const float* __restrict__ gy1,
                                                    const float* __restrict__ gx2,
                                                    const float* __restrict__ gy2,
                                                    const float* __restrict__ gsc,
                                                    const unsigned char* __restrict__ glv,
                                                    const int* __restrict__ gV,
                                                    float* __restrict__ out_boxes,
                                                    float* __restrict__ out_scores) {
    int b = blockIdx.x;
    int tid = threadIdx.x;
    int lane = tid & 63, wvi = tid >> 6;
    __shared__ unsigned short klist[POST_N];
    __shared__ int s_kc;
    int V = gV[b];

    if (wvi == 0) {
        const u64* M = mat + ((size_t)b << 18);
        u64 remv = 0;
        int kc = 0;
        u64 cur[16], nxt[16];
        #pragma unroll
        for (int e = 0; e < 16; ++e) cur[e] = M[((size_t)e << 6) + lane];
        for (int g = 0; g * 16 < V && kc < POST_N; ++g) {
            int gb = g * 16;
            #pragma unroll
            for (int e = 0; e < 16; ++e) {
                int i2 = gb + 16 + e;
                nxt[e] = (i2 < NSORT) ? M[((size_t)i2 << 6) + lane] : 0ull;
            }
            #pragma unroll
            for (int e = 0; e < 16; ++e) {
                int i = gb + e;
                if (i >= V || kc >= POST_N) break;
                int wi = i >> 6;
                u64 word = __shfl(remv, wi);
                if (!((word >> (i & 63)) & 1ull)) {
                    if (lane == 0) klist[kc] = (unsigned short)i;
                    kc++;
                    u64 row = (lane >= wi) ? cur[e] : 0ull;
                    remv |= row;
                }
            }
            #pragma unroll
            for (int e = 0; e < 16; ++e) cur[e] = nxt[e];
        }
        if (lane == 0) s_kc = kc;
    }
    __syncthreads();
    int kc = s_kc;

    float* ob = out_boxes + (size_t)b * POST_N * 4;
    float* os = out_scores + (size_t)b * POST_N;
    for (int q = tid; q < POST_N; q += 512) {
        ob[4 * q + 0] = 0.f; ob[4 * q + 1] = 0.f;
        ob[4 * q + 2] = 0.f; ob[4 * q + 3] = 0.f;
        os[q] = 0.f;
    }
    __syncthreads();
    size_t base = (size_t)b * NSORT;
    for (int p = tid; p < kc; p += 512) {
        int i = klist[p];
        float lo = (float)glv[base + i] * 1025.0f;
        ob[4 * p + 0] = gx1[base + i] - lo;
        ob[4 * p + 1] = gy1[base + i] - lo;
        ob[4 * p + 2] = gx2[base + i] - lo;
        ob[4 * p + 3] = gy2[base + i] - lo;
        os[p] = gsc[base + i];
    }
}

// ============ FALLBACK PATH (round-2, needs only 128 KB ws) ============

__global__ __launch_bounds__(512) void topk_kernel(const float* __restrict__ obj,
                                                   int* __restrict__ sel) {
    const int offs[4] = {0, 196608, 245760, 258048};
    const int ns[4]   = {196608, 49152, 12288, 3072};
    int blk = blockIdx.x;
    int b = blk >> 2, lvl = blk & 3;
    int off = offs[lvl], n = ns[lvl];
    const float* src = obj + (size_t)b * A_TOTAL + off;
    const float4* src4 = (const float4*)src;
    int n4 = n >> 2;

    __shared__ unsigned whist[8 * 2048];
    __shared__ int eqbuf[2048];
    __shared__ unsigned s_res[2];
    __shared__ unsigned swsum[8];
    __shared__ unsigned s_cnt, s_eq;
    int tid = threadIdx.x;
    int wv = tid >> 6;

    for (int i = tid; i < 8 * 2048; i += 512) whist[i] = 0;
    if (tid == 0) { s_cnt = 0; s_eq = 0; }
    __syncthreads();

    unsigned* myh = whist + wv * 2048;
    for (int i = tid; i < n4; i += 512) {
        float4 v = src4[i];
        atomicAdd(&myh[sortable(v.x) >> 21], 1u);
        atomicAdd(&myh[sortable(v.y) >> 21], 1u);
        atomicAdd(&myh[sortable(v.z) >> 21], 1u);
        atomicAdd(&myh[sortable(v.w) >> 21], 1u);
    }
    __syncthreads();
    for (int bin = tid; bin < 2048; bin += 512) {
        unsigned s = 0;
        #pragma unroll
        for (int w = 0; w < 8; ++w) s += whist[w * 2048 + bin];
        whist[bin] = s;
    }
    __syncthreads();
    radix_sel<2048>(whist, K_PER_LVL, s_res, swsum);
    unsigned T1 = s_res[0], G1 = s_res[1];

    for (int i = tid; i < 2048; i += 512) whist[i] = 0;
    __syncthreads();
    for (int i = tid; i < n4; i += 512) {
        float4 v = src4[i];
        unsigned k;
        k = sortable(v.x); if ((k >> 21) == T1) atomicAdd(&whist[(k >> 10) & 0x7FFu], 1u);
        k = sortable(v.y); if ((k >> 21) == T1) atomicAdd(&whist[(k >> 10) & 0x7FFu], 1u);
        k = sortable(v.z); if ((k >> 21) == T1) atomicAdd(&whist[(k >> 10) & 0x7FFu], 1u);
        k = sortable(v.w); if ((k >> 21) == T1) atomicAdd(&whist[(k >> 10) & 0x7FFu], 1u);
    }
    __syncthreads();
    radix_sel<2048>(whist, K_PER_LVL - G1, s_res, swsum);
    unsigned T2 = s_res[0], G2 = s_res[1];
    unsigned pref21 = (T1 << 11) | T2;

    for (int i = tid; i < 1024; i += 512) whist[i] = 0;
    __syncthreads();
    for (int i = tid; i < n4; i += 512) {
        float4 v = src4[i];
        unsigned k;
        k = sortable(v.x); if ((k >> 10) == pref21) atomicAdd(&whist[k & 0x3FFu], 1u);
        k = sortable(v.y); if ((k >> 10) == pref21) atomicAdd(&whist[k & 0x3FFu], 1u);
        k = sortable(v.z); if ((k >> 10) == pref21) atomicAdd(&whist[k & 0x3FFu], 1u);
        k = sortable(v.w); if ((k >> 10) == pref21) atomicAdd(&whist[k & 0x3FFu], 1u);
    }
    __syncthreads();
    radix_sel<1024>(whist, K_PER_LVL - G1 - G2, s_res, swsum);
    unsigned T3 = s_res[0], G3 = s_res[1];
    unsigned Kstar = (pref21 << 10) | T3;
    unsigned Gtot = G1 + G2 + G3;

    int* out = sel + (size_t)(b * 4 + lvl) * K_PER_LVL;
    for (int i4 = tid; i4 < n4; i4 += 512) {
        float4 v = src4[i4];
        float arr[4] = {v.x, v.y, v.z, v.w};
        #pragma unroll
        for (int c = 0; c < 4; ++c) {
            unsigned k = sortable(arr[c]);
            int i = 4 * i4 + c;
            if (k > Kstar) {
                unsigned p = atomicAdd(&s_cnt, 1u);
                out[p] = off + i;
            } else if (k == Kstar) {
                unsigned p = atomicAdd(&s_eq, 1u);
                if (p < 2048) eqbuf[p] = i;
            }
        }
    }
    __syncthreads();
    if (tid == 0) {
        int m = K_PER_LVL - (int)Gtot;
        int E = (int)min(s_eq, 2048u);
        int bse = (int)Gtot;
        int last = -1;
        for (int r = 0; r < m; ++r) {
            int best = 0x7FFFFFFF;
            for (int e = 0; e < E; ++e) {
                int v = eqbuf[e];
                if (v > last && v < best) best = v;
            }
            out[bse + r] = off + best;
            last = best;
        }
    }
}

__global__ __launch_bounds__(512) void nms_kernel(const float* __restrict__ obj,
                                                  const float* __restrict__ deltas,
                                                  const float* __restrict__ anchors,
                                                  const int* __restrict__ sel,
                                                  float* __restrict__ out_boxes,
                                                  float* __restrict__ out_scores) {
    int b = blockIdx.x;
    int tid = threadIdx.x;
    const int nth = 512;
    int lane = tid & 63, wvi = tid >> 6;

    __shared__ u64 key[NSORT];
    __shared__ float bx1[NSORT], by1[NSORT], bx2[NSORT], by2[NSORT], bar[NSORT];
    __shared__ unsigned char blv[NSORT];
    __shared__ unsigned char rm[NSORT];
    __shared__ u64 srow[64];
    __shared__ u64 s_alive;
    __shared__ int sV;
    __shared__ unsigned swsum[8];

    if (tid == 0) sV = K_TOTAL;

    for (int s = tid; s < NSORT; s += nth) {
        if (s < K_TOTAL) {
            int g = sel[(size_t)b * K_TOTAL + s];
            float score = obj[(size_t)b * A_TOTAL + g];
            float4 dl = *(const float4*)(deltas + ((size_t)b * A_TOTAL + g) * 4);
            float4 an = *(const float4*)(anchors + (size_t)g * 4);
            float wa = an.z - an.x, ha = an.w - an.y;
            float cxa = an.x + 0.5f * wa, cya = an.y + 0.5f * ha;
            float dw = fminf(dl.z, BBOX_CLIP), dh = fminf(dl.w, BBOX_CLIP);
            float cx = dl.x * wa + cxa, cy = dl.y * ha + cya;
            float w = expf(dw) * wa, h = expf(dh) * ha;
            float x1 = cx - 0.5f * w, y1 = cy - 0.5f * h;
            float x2 = cx + 0.5f * w, y2 = cy + 0.5f * h;
            x1 = fminf(fmaxf(x1, 0.f), 1024.f);
            y1 = fminf(fmaxf(y1, 0.f), 1024.f);
            x2 = fminf(fmaxf(x2, 0.f), 1024.f);
            y2 = fminf(fmaxf(y2, 0.f), 1024.f);
            bool valid = (x2 - x1 >= 0.001f) && (y2 - y1 >= 0.001f) && (score >= 0.f);
            float sm = valid ? score : NEGV;
            int lv = (g >= 258048) ? 3 : (g >= 245760) ? 2 : (g >= 196608) ? 1 : 0;
            float lo = (float)lv * 1025.0f;
            float xo1 = x1 + lo, yo1 = y1 + lo, xo2 = x2 + lo, yo2 = y2 + lo;
            bx1[s] = xo1; by1[s] = yo1; bx2[s] = xo2; by2[s] = yo2;
            bar[s] = (xo2 - xo1) * (yo2 - yo1);
            blv[s] = (unsigned char)lv;
            key[s] = ((u64)sortable(sm) << 32)
                   | ((u64)(0x3FFFFu - (unsigned)g) << 12)
                   | (unsigned)s;
        } else {
            bx1[s] = 0.f; by1[s] = 0.f; bx2[s] = 0.f; by2[s] = 0.f;
            bar[s] = 0.f; blv[s] = 0;
            key[s] = ((u64)sortable(NEGV) << 32) | (unsigned)s;
        }
    }
    __syncthreads();

    for (int k = 2; k <= NSORT; k <<= 1) {
        for (int j = k >> 1; j > 0; j >>= 1) {
            for (int i = tid; i < NSORT; i += nth) {
                int p = i ^ j;
                if (p > i) {
                    u64 a = key[i], c = key[p];
                    bool up = (i & k) == 0;
                    if (up ? (a < c) : (a > c)) { key[i] = c; key[p] = a; }
                }
            }
            __syncthreads();
        }
    }

    {
        float px1[8], py1[8], px2[8], py2[8], pa[8];
        unsigned char plv[8];
        #pragma unroll
        for (int e = 0; e < 8; ++e) {
            int i = tid * 8 + e;
            int slot = (int)(key[i] & 0xFFFull);
            px1[e] = bx1[slot]; py1[e] = by1[slot];
            px2[e] = bx2[slot]; py2[e] = by2[slot];
            pa[e] = bar[slot];  plv[e] = blv[slot];
            if (i < K_TOTAL && (unsigned)(key[i] >> 32) < 0x80000000u) atomicMin(&sV, i);
        }
        __syncthreads();
        #pragma unroll
        for (int e = 0; e < 8; ++e) {
            int i = tid * 8 + e;
            bx1[i] = px1[e]; by1[i] = py1[e];
            bx2[i] = px2[e]; by2[i] = py2[e];
            bar[i] = pa[e];  blv[i] = plv[e];
            rm[i] = 0;
        }
    }
    __syncthreads();
    int V = sV;

    int nchunk = (V + 63) >> 6;
    int kept_total = 0;
    for (int c = 0; c < nchunk; ++c) {
        int base = c << 6;
        int j = base + lane;
        bool jin = j < V;
        float jx1 = bx1[j], jy1 = by1[j], jx2 = bx2[j], jy2 = by2[j], ja = bar[j];

        #pragma unroll
        for (int kk = 0; kk < 8; ++kk) {
            int k = (wvi << 3) + kk;
            float kx1 = bx1[base + k], ky1 = by1[base + k];
            float kx2 = bx2[base + k], ky2 = by2[base + k], ka = bar[base + k];
            bool sup = false;
            if (jin && lane > k) {
                float lx = fmaxf(kx1, jx1), ly = fmaxf(ky1, jy1);
                float rx = fminf(kx2, jx2), ry = fminf(ky2, jy2);
                float wx = fmaxf(rx - lx, 0.f), wy = fmaxf(ry - ly, 0.f);
                float inter = wx * wy;
                float iou = inter / (ka + ja - inter + 1e-9f);
                sup = iou > 0.7f;
            }
            u64 r = __ballot(sup);
            if (lane == 0) srow[k] = r;
        }
        __syncthreads();

        if (wvi == 0) {
            u64 row = srow[lane];
            bool a0 = jin && (rm[j] == 0);
            u64 alive = __ballot(a0);
            u64 m = alive;
            while (m) {
                int k = __ffsll((long long)m) - 1;
                u64 r = __shfl(row, k);
                alive &= ~r;
                m &= alive;
                m &= ~(1ULL << k);
            }
            if (jin && a0 && !((alive >> lane) & 1)) rm[j] = 1;
            if (lane == 0) s_alive = alive;
        }
        __syncthreads();

        u64 aliveC = s_alive;
        kept_total += __popcll(aliveC);
        if (kept_total >= POST_N) break;

        for (int i = base + 64 + tid; i < V; i += nth) {
            if (rm[i]) continue;
            float ix1 = bx1[i], iy1 = by1[i], ix2 = bx2[i], iy2 = by2[i], ia = bar[i];
            u64 mm = aliveC;
            bool dead = false;
            while (mm) {
                int k = __ffsll((long long)mm) - 1; mm &= mm - 1;
                float kx1 = bx1[base + k], ky1 = by1[base + k];
                float kx2 = bx2[base + k], ky2 = by2[base + k], ka = bar[base + k];
                float lx = fmaxf(kx1, ix1), ly = fmaxf(ky1, iy1);
                float rx = fminf(kx2, ix2), ry = fminf(ky2, iy2);
                float wx = fmaxf(rx - lx, 0.f), wy = fmaxf(ry - ly, 0.f);
                float inter = wx * wy;
                float iou = inter / (ka + ia - inter + 1e-9f);
                if (iou > 0.7f) { dead = true; break; }
            }
            if (dead) rm[i] = 1;
        }
        __syncthreads();
    }
    __syncthreads();

    float* ob = out_boxes + (size_t)b * POST_N * 4;
    float* os = out_scores + (size_t)b * POST_N;
    for (int q = tid; q < POST_N; q += nth) {
        ob[4 * q + 0] = 0.f; ob[4 * q + 1] = 0.f;
        ob[4 * q + 2] = 0.f; ob[4 * q + 3] = 0.f;
        os[q] = 0.f;
    }
    __syncthreads();

    int cnt = 0;
    unsigned char kf[8];
    #pragma unroll
    for (int e = 0; e < 8; ++e) {
        int i = tid * 8 + e;
        int f = (i < V && rm[i] == 0) ? 1 : 0;
        kf[e] = (unsigned char)f; cnt += f;
    }
    int x = cnt;
    #pragma unroll
    for (int d = 1; d < 64; d <<= 1) {
        int y = __shfl_up(x, d);
        if (lane >= d) x += y;
    }
    if (lane == 63) swsum[wvi] = (unsigned)x;
    __syncthreads();
    int woff = 0;
    for (int w = 0; w < wvi; ++w) woff += (int)swsum[w];
    int p = woff + x - cnt;
    #pragma unroll
    for (int e = 0; e < 8; ++e) {
        if (kf[e]) {
            if (p < POST_N) {
                int i = tid * 8 + e;
                float lo = (float)blv[i] * 1025.0f;
                ob[4 * p + 0] = bx1[i] - lo;
                ob[4 * p + 1] = by1[i] - lo;
                ob[4 * p + 2] = bx2[i] - lo;
                ob[4 * p + 3] = by2[i] - lo;
                os[p] = unsortable((unsigned)(key[i] >> 32));
            }
            ++p;
        }
    }
}

extern "C" void kernel_launch(void* const* d_in, const int* in_sizes, int n_in,
                              void* d_out, int out_size, void* d_ws, size_t ws_size,
                              hipStream_t stream) {
    const float* obj     = (const float*)d_in[0];
    const float* deltas  = (const float*)d_in[1];
    const float* anchors = (const float*)d_in[2];
    float* out_boxes  = (float*)d_out;
    float* out_scores = (float*)d_out + B_BATCH * POST_N * 4;
    char* ws = (char*)d_ws;

    const size_t O_SEL  = 0;        // int[8][4000]           = 128000
    const size_t O_HIST = 131072;   // u32[32][2048]          = 262144
    const size_t O_BX1  = 393216;   // f32[8][4096] each ↓    = 131072
    const size_t O_BY1  = 524288;
    const size_t O_BX2  = 655360;
    const size_t O_BY2  = 786432;
    const size_t O_BAR  = 917504;
    const size_t O_BSC  = 1048576;
    const size_t O_BLV  = 1179648;  // u8[8][4096]            = 32768
    const size_t O_BV   = 1212416;  // int[8]
    const size_t O_MAT  = 2097152;  // u64[8][4096][64]       = 16777216
    const size_t NEED   = O_MAT + (size_t)16777216;

    if (ws_size >= NEED) {
        hipMemsetAsync(ws + O_HIST, 0, 262144, stream);
        topk_hist<<<512, 512, 0, stream>>>(obj, (unsigned*)(ws + O_HIST));
        topk_select<<<32, 512, 0, stream>>>(obj, (const unsigned*)(ws + O_HIST),
                                            (int*)(ws + O_SEL));
        decode_sort<<<8, 512, 0, stream>>>(obj, deltas, anchors, (const int*)(ws + O_SEL),
                                           (float*)(ws + O_BX1), (float*)(ws + O_BY1),
                                           (float*)(ws + O_BX2), (float*)(ws + O_BY2),
                                           (float*)(ws + O_BAR), (float*)(ws + O_BSC),
                                           (unsigned char*)(ws + O_BLV), (int*)(ws + O_BV));
        build_mat<<<512, 512, 0, stream>>>((const float*)(ws + O_BX1), (const float*)(ws + O_BY1),
                                           (const float*)(ws + O_BX2), (const float*)(ws + O_BY2),
                                           (const float*)(ws + O_BAR), (const int*)(ws + O_BV),
                                           (u64*)(ws + O_MAT));
        resolve_emit<<<8, 512, 0, stream>>>((const u64*)(ws + O_MAT),
                                            (const float*)(ws + O_BX1), (const float*)(ws + O_BY1),
                                            (const float*)(ws + O_BX2), (const float*)(ws + O_BY2),
                                            (const float*)(ws + O_BSC),
                                            (const unsigned char*)(ws + O_BLV),
                                            (const int*)(ws + O_BV),
                                            out_boxes, out_scores);
    } else {
        topk_kernel<<<32, 512, 0, stream>>>(obj, (int*)ws);
        nms_kernel<<<B_BATCH, 512, 0, stream>>>(obj, deltas, anchors, (const int*)ws,
                                                out_boxes, out_scores);
    }
}